// Round 1
// baseline (911.471 us; speedup 1.0000x reference)
//
#include <hip/hip_runtime.h>
#include <hip/hip_bf16.h>
#include <cstdint>
#include <cstddef>

#define B_ 4
#define N_ 10000
#define E_ 160000
#define H_ 128
#define HEADS_ 4
#define HH_ 512
#define NROWS (B_*N_)

__device__ __forceinline__ float lrelu(float x){ return x > 0.f ? x : 0.2f*x; }

// ---------------- CSR build (tgt -> list of src), once per launch ----------------
__global__ void k_count(const int* __restrict__ tgt, int* __restrict__ cnt){
  int e = blockIdx.x*blockDim.x + threadIdx.x;
  int b = blockIdx.y;
  int t = tgt[(size_t)b*E_ + e];
  atomicAdd(&cnt[b*N_ + t], 1);
}

__global__ void k_scan(const int* __restrict__ cnt, int* __restrict__ off, int* __restrict__ cursor){
  int b = blockIdx.x;
  __shared__ int wsum[16];
  __shared__ int carry_s;
  int lane = threadIdx.x & 63, wid = threadIdx.x >> 6;
  if (threadIdx.x == 0){ carry_s = 0; off[b*(N_+1)] = 0; }
  __syncthreads();
  for (int base = 0; base < N_; base += 1024){
    int i = base + threadIdx.x;
    int v = (i < N_) ? cnt[b*N_ + i] : 0;
    int x = v;
    #pragma unroll
    for (int d = 1; d < 64; d <<= 1){
      int y = __shfl_up(x, d);
      if (lane >= d) x += y;
    }
    if (lane == 63) wsum[wid] = x;
    __syncthreads();
    if (wid == 0 && lane < 16){
      int w = wsum[lane];
      #pragma unroll
      for (int d = 1; d < 16; d <<= 1){
        int y = __shfl_up(w, d, 16);
        if (lane >= d) w += y;
      }
      wsum[lane] = w;
    }
    __syncthreads();
    int excl = (wid ? wsum[wid-1] : 0) + carry_s;
    if (i < N_){
      int inc = x + excl;
      off[b*(N_+1) + i + 1] = inc;
      cursor[b*N_ + i] = inc - v;   // exclusive prefix = start slot
    }
    __syncthreads();
    if (threadIdx.x == 0) carry_s += wsum[15];
    __syncthreads();
  }
}

__global__ void k_scatter(const int* __restrict__ src, const int* __restrict__ tgt,
                          int* __restrict__ cursor, int* __restrict__ csr){
  int e = blockIdx.x*blockDim.x + threadIdx.x;
  int b = blockIdx.y;
  int t = tgt[(size_t)b*E_ + e];
  int pos = atomicAdd(&cursor[b*N_ + t], 1);
  csr[(size_t)b*E_ + pos] = src[(size_t)b*E_ + e];
}

// ---------------- Wa[k][head] = sum_c W[k][head*H+c] * a[head][c] ----------------
__global__ void k_wa(const float* __restrict__ W, const float* __restrict__ as_,
                     const float* __restrict__ ad_, float* __restrict__ was, float* __restrict__ wad){
  int i = blockIdx.x*blockDim.x + threadIdx.x;   // i = k*4 + head
  if (i >= H_*HEADS_) return;
  int k = i >> 2, h = i & 3;
  const float* wrow = W + (size_t)k*HH_ + h*H_;
  const float* asr = as_ + h*H_;
  const float* adr = ad_ + h*H_;
  float ss = 0.f, sd = 0.f;
  for (int c = 0; c < H_; ++c){ float w = wrow[c]; ss += w*asr[c]; sd += w*adr[c]; }
  was[i] = ss; wad[i] = sd;
}

// ---------------- e_src/e_dst = x @ Wa  (one wave per node) ----------------
__global__ __launch_bounds__(256) void k_logits(const float* __restrict__ X,
    const float* __restrict__ was, const float* __restrict__ wad,
    float* __restrict__ es, float* __restrict__ ed){
  int gw = (blockIdx.x * blockDim.x + threadIdx.x) >> 6;
  int lane = threadIdx.x & 63;
  const float2 xv = *(const float2*)(X + (size_t)gw*H_ + lane*2);
  float4 w0 = *(const float4*)(was + lane*8);
  float4 w1 = *(const float4*)(was + lane*8 + 4);
  float4 d0 = *(const float4*)(wad + lane*8);
  float4 d1 = *(const float4*)(wad + lane*8 + 4);
  float s0 = xv.x*w0.x + xv.y*w1.x;
  float s1 = xv.x*w0.y + xv.y*w1.y;
  float s2 = xv.x*w0.z + xv.y*w1.z;
  float s3 = xv.x*w0.w + xv.y*w1.w;
  float t0 = xv.x*d0.x + xv.y*d1.x;
  float t1 = xv.x*d0.y + xv.y*d1.y;
  float t2 = xv.x*d0.z + xv.y*d1.z;
  float t3 = xv.x*d0.w + xv.y*d1.w;
  #pragma unroll
  for (int d = 1; d < 64; d <<= 1){
    s0 += __shfl_xor(s0, d); s1 += __shfl_xor(s1, d);
    s2 += __shfl_xor(s2, d); s3 += __shfl_xor(s3, d);
    t0 += __shfl_xor(t0, d); t1 += __shfl_xor(t1, d);
    t2 += __shfl_xor(t2, d); t3 += __shfl_xor(t3, d);
  }
  if (lane == 0){
    *(float4*)(es + (size_t)gw*4) = make_float4(s0, s1, s2, s3);
    *(float4*)(ed + (size_t)gw*4) = make_float4(t0, t1, t2, t3);
  }
}

// ---------------- h = x @ W  (f32 tiled GEMM: 128x64 tile, K-step 32) ----------------
__global__ __launch_bounds__(256) void k_gemm(const float* __restrict__ X,
    const float* __restrict__ W, float* __restrict__ Hout){
  __shared__ float xs[32][132];   // [k][row], padded (132*4=528B rows: 16B aligned)
  __shared__ float ws[32][64];    // [k][col]
  int row0 = blockIdx.x * 128;
  int col0 = blockIdx.y * 64;
  int tid = threadIdx.x;
  float acc[8][4];
  #pragma unroll
  for (int i = 0; i < 8; i++)
    #pragma unroll
    for (int j = 0; j < 4; j++) acc[i][j] = 0.f;
  int k4 = tid & 7, rr = tid >> 3;
  int c4 = tid & 15, wr = tid >> 4;
  int ty = tid >> 4, tx = tid & 15;
  for (int kk = 0; kk < H_; kk += 32){
    #pragma unroll
    for (int p = 0; p < 4; p++){
      int r = rr + p*32;
      int gr = row0 + r;
      float4 v = make_float4(0.f,0.f,0.f,0.f);
      if (gr < NROWS) v = *(const float4*)(X + (size_t)gr*H_ + kk + k4*4);
      xs[k4*4+0][r] = v.x; xs[k4*4+1][r] = v.y; xs[k4*4+2][r] = v.z; xs[k4*4+3][r] = v.w;
    }
    #pragma unroll
    for (int p = 0; p < 2; p++){
      int k = wr + p*16;
      float4 v = *(const float4*)(W + (size_t)(kk+k)*HH_ + col0 + c4*4);
      *(float4*)(&ws[k][c4*4]) = v;
    }
    __syncthreads();
    #pragma unroll
    for (int k = 0; k < 32; k++){
      float4 bv = *(const float4*)(&ws[k][tx*4]);
      float4 a0 = *(const float4*)(&xs[k][ty*8]);
      float4 a1 = *(const float4*)(&xs[k][ty*8+4]);
      float av[8] = {a0.x,a0.y,a0.z,a0.w,a1.x,a1.y,a1.z,a1.w};
      float bb[4] = {bv.x,bv.y,bv.z,bv.w};
      #pragma unroll
      for (int i = 0; i < 8; i++)
        #pragma unroll
        for (int j = 0; j < 4; j++)
          acc[i][j] += av[i]*bb[j];
    }
    __syncthreads();
  }
  #pragma unroll
  for (int i = 0; i < 8; i++){
    int gr = row0 + ty*8 + i;
    if (gr < NROWS){
      float4 o = make_float4(acc[i][0], acc[i][1], acc[i][2], acc[i][3]);
      *(float4*)(Hout + (size_t)gr*HH_ + col0 + tx*4) = o;
    }
  }
}

// ---------------- per-target softmax + weighted aggregation (one wave per node) ----------------
__global__ __launch_bounds__(256) void k_aggregate(const float* __restrict__ Hf,
    const float* __restrict__ es, const float* __restrict__ ed,
    const int* __restrict__ off, const int* __restrict__ csr,
    const float* __restrict__ bias, float* __restrict__ Y){
  int gw = (blockIdx.x * blockDim.x + threadIdx.x) >> 6;
  int lane = threadIdx.x & 63;
  int b = gw / N_;
  int t = gw - b*N_;
  const float4 edv = *(const float4*)(ed + (size_t)gw*4);
  int start = off[b*(N_+1) + t];
  int deg = off[b*(N_+1) + t + 1] - start;    // real in-edges; +1 implicit self-loop
  const int* lst = csr + (size_t)b*E_ + start;

  // phase A: online softmax stats (per-lane, then 6-step merge)
  float m0=-1e30f, m1=-1e30f, m2=-1e30f, m3=-1e30f;
  float s0=0.f, s1=0.f, s2=0.f, s3=0.f;
  for (int i = lane; i <= deg; i += 64){
    int srcn = (i < deg) ? lst[i] : t;
    float4 ev = *(const float4*)(es + (size_t)(b*N_ + srcn)*4);
    float e0 = lrelu(ev.x + edv.x);
    float e1 = lrelu(ev.y + edv.y);
    float e2 = lrelu(ev.z + edv.z);
    float e3 = lrelu(ev.w + edv.w);
    float nm;
    nm = fmaxf(m0, e0); s0 = s0*__expf(m0-nm) + __expf(e0-nm); m0 = nm;
    nm = fmaxf(m1, e1); s1 = s1*__expf(m1-nm) + __expf(e1-nm); m1 = nm;
    nm = fmaxf(m2, e2); s2 = s2*__expf(m2-nm) + __expf(e2-nm); m2 = nm;
    nm = fmaxf(m3, e3); s3 = s3*__expf(m3-nm) + __expf(e3-nm); m3 = nm;
  }
  #pragma unroll
  for (int d = 1; d < 64; d <<= 1){
    float om, os, nm;
    om = __shfl_xor(m0, d); os = __shfl_xor(s0, d); nm = fmaxf(m0, om);
    s0 = s0*__expf(m0-nm) + os*__expf(om-nm); m0 = nm;
    om = __shfl_xor(m1, d); os = __shfl_xor(s1, d); nm = fmaxf(m1, om);
    s1 = s1*__expf(m1-nm) + os*__expf(om-nm); m1 = nm;
    om = __shfl_xor(m2, d); os = __shfl_xor(s2, d); nm = fmaxf(m2, om);
    s2 = s2*__expf(m2-nm) + os*__expf(om-nm); m2 = nm;
    om = __shfl_xor(m3, d); os = __shfl_xor(s3, d); nm = fmaxf(m3, om);
    s3 = s3*__expf(m3-nm) + os*__expf(om-nm); m3 = nm;
  }

  // phase B: weighted sum. lane -> (head = lane/16, 8 channels)
  int head = lane >> 4;
  float mh, sh, edh;
  if      (head == 0){ mh = m0; sh = s0; edh = edv.x; }
  else if (head == 1){ mh = m1; sh = s1; edh = edv.y; }
  else if (head == 2){ mh = m2; sh = s2; edh = edv.z; }
  else               { mh = m3; sh = s3; edh = edv.w; }
  float rh = 1.0f / sh;
  int cb = head*H_ + (lane & 15)*8;
  const float* hbase = Hf + (size_t)b*N_*HH_;
  float a[8] = {0.f,0.f,0.f,0.f,0.f,0.f,0.f,0.f};
  for (int i = 0; i <= deg; ++i){
    int srcn = (i < deg) ? lst[i] : t;
    float eh = es[(size_t)(b*N_ + srcn)*4 + head];
    float e = lrelu(eh + edh);
    float alpha = __expf(e - mh) * rh;
    const float4* hp = (const float4*)(hbase + (size_t)srcn*HH_ + cb);
    float4 h0 = hp[0], h1 = hp[1];
    a[0] += alpha*h0.x; a[1] += alpha*h0.y; a[2] += alpha*h0.z; a[3] += alpha*h0.w;
    a[4] += alpha*h1.x; a[5] += alpha*h1.y; a[6] += alpha*h1.z; a[7] += alpha*h1.w;
  }
  // head mean: sum lanes {l, l^16, l^32, l^48}
  #pragma unroll
  for (int d = 16; d < 64; d <<= 1)
    #pragma unroll
    for (int j = 0; j < 8; j++) a[j] += __shfl_xor(a[j], d);
  if (lane < 16){
    int c = lane*8;
    float4 o0 = make_float4(0.25f*a[0]+bias[c+0], 0.25f*a[1]+bias[c+1],
                            0.25f*a[2]+bias[c+2], 0.25f*a[3]+bias[c+3]);
    float4 o1 = make_float4(0.25f*a[4]+bias[c+4], 0.25f*a[5]+bias[c+5],
                            0.25f*a[6]+bias[c+6], 0.25f*a[7]+bias[c+7]);
    *(float4*)(Y + (size_t)gw*H_ + c)     = o0;
    *(float4*)(Y + (size_t)gw*H_ + c + 4) = o1;
  }
}

// ---------------- LayerNorm + ReLU, in place (one wave per row) ----------------
__global__ __launch_bounds__(256) void k_lnrelu(float* __restrict__ Y,
    const float* __restrict__ g, const float* __restrict__ bb){
  int gw = (blockIdx.x*blockDim.x + threadIdx.x) >> 6;
  int lane = threadIdx.x & 63;
  float2 v = *(const float2*)(Y + (size_t)gw*H_ + lane*2);
  float sum = v.x + v.y;
  #pragma unroll
  for (int d = 1; d < 64; d <<= 1) sum += __shfl_xor(sum, d);
  float mu = sum * (1.f/H_);
  float dx = v.x - mu, dy = v.y - mu;
  float vs = dx*dx + dy*dy;
  #pragma unroll
  for (int d = 1; d < 64; d <<= 1) vs += __shfl_xor(vs, d);
  float inv = rsqrtf(vs*(1.f/H_) + 1e-5f);
  float2 gv = *(const float2*)(g + lane*2);
  float2 bv = *(const float2*)(bb + lane*2);
  float ox = fmaxf(dx*inv*gv.x + bv.x, 0.f);
  float oy = fmaxf(dy*inv*gv.y + bv.y, 0.f);
  *(float2*)(Y + (size_t)gw*H_ + lane*2) = make_float2(ox, oy);
}

extern "C" void kernel_launch(void* const* d_in, const int* in_sizes, int n_in,
                              void* d_out, int out_size, void* d_ws, size_t ws_size,
                              hipStream_t stream){
  const float* x0   = (const float*)d_in[0];
  const int*   srcI = (const int*)d_in[1];
  const int*   tgtI = (const int*)d_in[2];
  const float* Wl[3]  = {(const float*)d_in[3], (const float*)d_in[7],  (const float*)d_in[11]};
  const float* asl[3] = {(const float*)d_in[4], (const float*)d_in[8],  (const float*)d_in[12]};
  const float* adl[3] = {(const float*)d_in[5], (const float*)d_in[9],  (const float*)d_in[13]};
  const float* bl[3]  = {(const float*)d_in[6], (const float*)d_in[10], (const float*)d_in[14]};
  const float* lng[2] = {(const float*)d_in[15], (const float*)d_in[17]};
  const float* lnb[2] = {(const float*)d_in[16], (const float*)d_in[18]};

  char* p = (char*)d_ws;
  auto carve = [&](size_t bytes) -> void* {
    void* r = (void*)p; p += (bytes + 255) & ~(size_t)255; return r;
  };
  int*   off    = (int*)carve((size_t)B_*(N_+1)*4);
  int*   cnt    = (int*)carve((size_t)B_*N_*4);
  int*   cursor = (int*)carve((size_t)B_*N_*4);
  int*   csr    = (int*)carve((size_t)B_*E_*4);
  float* es     = (float*)carve((size_t)B_*N_*HEADS_*4);
  float* ed     = (float*)carve((size_t)B_*N_*HEADS_*4);
  float* was    = (float*)carve((size_t)H_*HEADS_*4);
  float* wad    = (float*)carve((size_t)H_*HEADS_*4);
  float* hbuf   = (float*)carve((size_t)NROWS*HH_*4);
  float* tbuf   = (float*)carve((size_t)NROWS*H_*4);

  hipMemsetAsync(cnt, 0, (size_t)B_*N_*4, stream);
  k_count  <<<dim3(E_/256, B_), 256, 0, stream>>>(tgtI, cnt);
  k_scan   <<<B_, 1024, 0, stream>>>(cnt, off, cursor);
  k_scatter<<<dim3(E_/256, B_), 256, 0, stream>>>(srcI, tgtI, cursor, csr);

  const float* xin = x0;
  for (int l = 0; l < 3; ++l){
    k_wa    <<<2, 256, 0, stream>>>(Wl[l], asl[l], adl[l], was, wad);
    k_logits<<<NROWS/4, 256, 0, stream>>>(xin, was, wad, es, ed);
    k_gemm  <<<dim3((NROWS+127)/128, HH_/64), 256, 0, stream>>>(xin, Wl[l], hbuf);
    float* yout = (l == 2) ? (float*)d_out : tbuf;
    k_aggregate<<<NROWS/4, 256, 0, stream>>>(hbuf, es, ed, off, csr, bl[l], yout);
    if (l < 2){
      k_lnrelu<<<NROWS/4, 256, 0, stream>>>(tbuf, lng[l], lnb[l]);
      xin = tbuf;
    }
  }
}

// Round 2
// 518.231 us; speedup vs baseline: 1.7588x; 1.7588x over previous
//
#include <hip/hip_runtime.h>
#include <hip/hip_bf16.h>
#include <cstdint>
#include <cstddef>

#define B_ 4
#define N_ 10000
#define E_ 160000
#define H_ 128
#define HEADS_ 4
#define HH_ 512
#define NROWS (B_*N_)

typedef __attribute__((ext_vector_type(8))) short bf16x8;
typedef __attribute__((ext_vector_type(4))) float f32x4;

__device__ __forceinline__ float lrelu(float x){ return x > 0.f ? x : 0.2f*x; }
__device__ __forceinline__ unsigned short f2b(float f){
  unsigned int u = __builtin_bit_cast(unsigned int, f);
  unsigned int r = (u + 0x7fffu + ((u >> 16) & 1u)) >> 16;
  return (unsigned short)r;
}
__device__ __forceinline__ float blo(unsigned int u){ return __builtin_bit_cast(float, u << 16); }
__device__ __forceinline__ float bhi(unsigned int u){ return __builtin_bit_cast(float, u & 0xffff0000u); }

// ---------------- CSR build (tgt -> list of src), once per launch ----------------
__global__ void k_count(const int* __restrict__ tgt, int* __restrict__ cnt){
  int e = blockIdx.x*blockDim.x + threadIdx.x;
  int b = blockIdx.y;
  int t = tgt[(size_t)b*E_ + e];
  atomicAdd(&cnt[b*N_ + t], 1);
}

__global__ void k_scan(const int* __restrict__ cnt, int* __restrict__ off, int* __restrict__ cursor){
  int b = blockIdx.x;
  __shared__ int wsum[16];
  __shared__ int carry_s;
  int lane = threadIdx.x & 63, wid = threadIdx.x >> 6;
  if (threadIdx.x == 0){ carry_s = 0; off[b*(N_+1)] = 0; }
  __syncthreads();
  for (int base = 0; base < N_; base += 1024){
    int i = base + threadIdx.x;
    int v = (i < N_) ? cnt[b*N_ + i] : 0;
    int x = v;
    #pragma unroll
    for (int d = 1; d < 64; d <<= 1){
      int y = __shfl_up(x, d);
      if (lane >= d) x += y;
    }
    if (lane == 63) wsum[wid] = x;
    __syncthreads();
    if (wid == 0 && lane < 16){
      int w = wsum[lane];
      #pragma unroll
      for (int d = 1; d < 16; d <<= 1){
        int y = __shfl_up(w, d, 16);
        if (lane >= d) w += y;
      }
      wsum[lane] = w;
    }
    __syncthreads();
    int excl = (wid ? wsum[wid-1] : 0) + carry_s;
    if (i < N_){
      int inc = x + excl;
      off[b*(N_+1) + i + 1] = inc;
      cursor[b*N_ + i] = inc - v;
    }
    __syncthreads();
    if (threadIdx.x == 0) carry_s += wsum[15];
    __syncthreads();
  }
}

__global__ void k_scatter(const int* __restrict__ src, const int* __restrict__ tgt,
                          int* __restrict__ cursor, int* __restrict__ csr){
  int e = blockIdx.x*blockDim.x + threadIdx.x;
  int b = blockIdx.y;
  int t = tgt[(size_t)b*E_ + e];
  int pos = atomicAdd(&cursor[b*N_ + t], 1);
  csr[(size_t)b*E_ + pos] = src[(size_t)b*E_ + e];
}

// ---------------- Wa[k][head] ----------------
__global__ void k_wa(const float* __restrict__ W, const float* __restrict__ as_,
                     const float* __restrict__ ad_, float* __restrict__ was, float* __restrict__ wad){
  int i = blockIdx.x*blockDim.x + threadIdx.x;   // i = k*4 + head
  if (i >= H_*HEADS_) return;
  int k = i >> 2, h = i & 3;
  const float* wrow = W + (size_t)k*HH_ + h*H_;
  const float* asr = as_ + h*H_;
  const float* adr = ad_ + h*H_;
  float ss = 0.f, sd = 0.f;
  for (int c = 0; c < H_; ++c){ float w = wrow[c]; ss += w*asr[c]; sd += w*adr[c]; }
  was[i] = ss; wad[i] = sd;
}

// ---------------- W transpose + cast: Wt[c][k] = bf16(W[k][c]) ----------------
__global__ void k_wprep(const float* __restrict__ W, unsigned short* __restrict__ Wt){
  int i = blockIdx.x*blockDim.x + threadIdx.x;   // i = c*H_ + k
  int c = i >> 7, k = i & 127;
  Wt[i] = f2b(W[(size_t)k*HH_ + c]);
}

// ---------------- cast f32 -> bf16 (layer-1 input) ----------------
__global__ __launch_bounds__(256) void k_cast(const float* __restrict__ X, unsigned short* __restrict__ Xb){
  int i = blockIdx.x*blockDim.x + threadIdx.x;
  float4 v = ((const float4*)X)[i];
  ushort4 o; o.x = f2b(v.x); o.y = f2b(v.y); o.z = f2b(v.z); o.w = f2b(v.w);
  ((ushort4*)Xb)[i] = o;
}

// ---------------- e_src/e_dst = x @ Wa  (one wave per node, bf16 x) ----------------
__global__ __launch_bounds__(256) void k_logits(const unsigned short* __restrict__ Xb,
    const float* __restrict__ was, const float* __restrict__ wad,
    float* __restrict__ es, float* __restrict__ ed){
  int gw = (blockIdx.x * blockDim.x + threadIdx.x) >> 6;
  int lane = threadIdx.x & 63;
  unsigned int u = *(const unsigned int*)(Xb + (size_t)gw*H_ + lane*2);
  float xlo = blo(u), xhi = bhi(u);
  float4 w0 = *(const float4*)(was + lane*8);
  float4 w1 = *(const float4*)(was + lane*8 + 4);
  float4 d0 = *(const float4*)(wad + lane*8);
  float4 d1 = *(const float4*)(wad + lane*8 + 4);
  float s0 = xlo*w0.x + xhi*w1.x;
  float s1 = xlo*w0.y + xhi*w1.y;
  float s2 = xlo*w0.z + xhi*w1.z;
  float s3 = xlo*w0.w + xhi*w1.w;
  float t0 = xlo*d0.x + xhi*d1.x;
  float t1 = xlo*d0.y + xhi*d1.y;
  float t2 = xlo*d0.z + xhi*d1.z;
  float t3 = xlo*d0.w + xhi*d1.w;
  #pragma unroll
  for (int d = 1; d < 64; d <<= 1){
    s0 += __shfl_xor(s0, d); s1 += __shfl_xor(s1, d);
    s2 += __shfl_xor(s2, d); s3 += __shfl_xor(s3, d);
    t0 += __shfl_xor(t0, d); t1 += __shfl_xor(t1, d);
    t2 += __shfl_xor(t2, d); t3 += __shfl_xor(t3, d);
  }
  if (lane == 0){
    *(float4*)(es + (size_t)gw*4) = make_float4(s0, s1, s2, s3);
    *(float4*)(ed + (size_t)gw*4) = make_float4(t0, t1, t2, t3);
  }
}

// ---------------- h = x @ W  (bf16 MFMA 16x16x32; 64x64 tile, full K=128 in LDS) ----------------
__global__ __launch_bounds__(256) void k_gemm_mfma(const unsigned short* __restrict__ Xb,
    const unsigned short* __restrict__ Wt, unsigned short* __restrict__ Hb){
  __shared__ unsigned short xs[64*128];   // [row][k], 16B-chunk XOR-swizzled by (row&7)
  __shared__ unsigned short ws[64*128];   // [col][k], same swizzle
  int row0 = blockIdx.x * 64, col0 = blockIdx.y * 64;
  int tid = threadIdx.x;
  int ch = tid & 15, r0 = tid >> 4;
  #pragma unroll
  for (int p = 0; p < 4; ++p){
    int r = r0 + p*16;
    int sc = ch ^ (r & 7);
    *(uint4*)(&xs[r*128 + sc*8]) = *(const uint4*)(Xb + (size_t)(row0 + r)*H_ + ch*8);
    *(uint4*)(&ws[r*128 + sc*8]) = *(const uint4*)(Wt + (size_t)(col0 + r)*H_ + ch*8);
  }
  __syncthreads();
  int w = tid >> 6, l = tid & 63;
  int lr = l & 15, q = l >> 4;
  f32x4 z = {0.f, 0.f, 0.f, 0.f};
  f32x4 acc[4] = {z, z, z, z};
  int arow = w*16 + lr;
  #pragma unroll
  for (int kf = 0; kf < 4; ++kf){
    int bch = kf*4 + q;
    bf16x8 a = *(const bf16x8*)(&xs[arow*128 + (bch ^ (arow & 7))*8]);
    #pragma unroll
    for (int cf = 0; cf < 4; ++cf){
      int brow = cf*16 + lr;
      bf16x8 bfr = *(const bf16x8*)(&ws[brow*128 + (bch ^ (brow & 7))*8]);
      acc[cf] = __builtin_amdgcn_mfma_f32_16x16x32_bf16(a, bfr, acc[cf], 0, 0, 0);
    }
  }
  #pragma unroll
  for (int cf = 0; cf < 4; ++cf){
    #pragma unroll
    for (int rg = 0; rg < 4; ++rg){
      int row = row0 + w*16 + q*4 + rg;
      int col = col0 + cf*16 + lr;
      Hb[(size_t)row*HH_ + col] = f2b(acc[cf][rg]);
    }
  }
}

// ---------------- per-target softmax + weighted aggregation (one wave per node) ----------------
__global__ __launch_bounds__(256) void k_aggregate(const unsigned short* __restrict__ Hb,
    const float* __restrict__ es, const float* __restrict__ ed,
    const int* __restrict__ off, const int* __restrict__ csr,
    const float* __restrict__ bias, float* __restrict__ Y){
  int gw = (blockIdx.x * blockDim.x + threadIdx.x) >> 6;
  int lane = threadIdx.x & 63;
  int b = gw / N_;
  int t = gw - b*N_;
  const float4 edv = *(const float4*)(ed + (size_t)gw*4);
  int start = off[b*(N_+1) + t];
  int deg = off[b*(N_+1) + t + 1] - start;
  const int* lst = csr + (size_t)b*E_ + start;

  // phase A: online softmax stats
  float m0=-1e30f, m1=-1e30f, m2=-1e30f, m3=-1e30f;
  float s0=0.f, s1=0.f, s2=0.f, s3=0.f;
  for (int i = lane; i <= deg; i += 64){
    int srcn = (i < deg) ? lst[i] : t;
    float4 ev = *(const float4*)(es + (size_t)(b*N_ + srcn)*4);
    float e0 = lrelu(ev.x + edv.x);
    float e1 = lrelu(ev.y + edv.y);
    float e2 = lrelu(ev.z + edv.z);
    float e3 = lrelu(ev.w + edv.w);
    float nm;
    nm = fmaxf(m0, e0); s0 = s0*__expf(m0-nm) + __expf(e0-nm); m0 = nm;
    nm = fmaxf(m1, e1); s1 = s1*__expf(m1-nm) + __expf(e1-nm); m1 = nm;
    nm = fmaxf(m2, e2); s2 = s2*__expf(m2-nm) + __expf(e2-nm); m2 = nm;
    nm = fmaxf(m3, e3); s3 = s3*__expf(m3-nm) + __expf(e3-nm); m3 = nm;
  }
  #pragma unroll
  for (int d = 1; d < 64; d <<= 1){
    float om, os, nm;
    om = __shfl_xor(m0, d); os = __shfl_xor(s0, d); nm = fmaxf(m0, om);
    s0 = s0*__expf(m0-nm) + os*__expf(om-nm); m0 = nm;
    om = __shfl_xor(m1, d); os = __shfl_xor(s1, d); nm = fmaxf(m1, om);
    s1 = s1*__expf(m1-nm) + os*__expf(om-nm); m1 = nm;
    om = __shfl_xor(m2, d); os = __shfl_xor(s2, d); nm = fmaxf(m2, om);
    s2 = s2*__expf(m2-nm) + os*__expf(om-nm); m2 = nm;
    om = __shfl_xor(m3, d); os = __shfl_xor(s3, d); nm = fmaxf(m3, om);
    s3 = s3*__expf(m3-nm) + os*__expf(om-nm); m3 = nm;
  }

  // phase B: weighted sum over bf16 h rows. lane -> (head = lane/16, 8 channels)
  int head = lane >> 4;
  float mh, sh, edh;
  if      (head == 0){ mh = m0; sh = s0; edh = edv.x; }
  else if (head == 1){ mh = m1; sh = s1; edh = edv.y; }
  else if (head == 2){ mh = m2; sh = s2; edh = edv.z; }
  else               { mh = m3; sh = s3; edh = edv.w; }
  float rh = 1.0f / sh;
  int cb = head*H_ + (lane & 15)*8;
  const unsigned short* hbase = Hb + (size_t)b*N_*HH_;
  const float* esb = es + (size_t)b*N_*4;
  float a[8] = {0.f,0.f,0.f,0.f,0.f,0.f,0.f,0.f};
  int total = deg + 1;    // + implicit self-loop
  int i = 0;
  for (; i + 1 < total; i += 2){
    int sA = lst[i];                       // i < deg guaranteed
    int sB = (i + 1 < deg) ? lst[i+1] : t;
    float eA = esb[(size_t)sA*4 + head];
    float eB = esb[(size_t)sB*4 + head];
    uint4 hA = *(const uint4*)(hbase + (size_t)sA*HH_ + cb);
    uint4 hB = *(const uint4*)(hbase + (size_t)sB*HH_ + cb);
    float aA = __expf(lrelu(eA + edh) - mh) * rh;
    float aB = __expf(lrelu(eB + edh) - mh) * rh;
    a[0] += aA*blo(hA.x); a[1] += aA*bhi(hA.x);
    a[2] += aA*blo(hA.y); a[3] += aA*bhi(hA.y);
    a[4] += aA*blo(hA.z); a[5] += aA*bhi(hA.z);
    a[6] += aA*blo(hA.w); a[7] += aA*bhi(hA.w);
    a[0] += aB*blo(hB.x); a[1] += aB*bhi(hB.x);
    a[2] += aB*blo(hB.y); a[3] += aB*bhi(hB.y);
    a[4] += aB*blo(hB.z); a[5] += aB*bhi(hB.z);
    a[6] += aB*blo(hB.w); a[7] += aB*bhi(hB.w);
  }
  if (i < total){
    int sA = (i < deg) ? lst[i] : t;
    float eA = esb[(size_t)sA*4 + head];
    uint4 hA = *(const uint4*)(hbase + (size_t)sA*HH_ + cb);
    float aA = __expf(lrelu(eA + edh) - mh) * rh;
    a[0] += aA*blo(hA.x); a[1] += aA*bhi(hA.x);
    a[2] += aA*blo(hA.y); a[3] += aA*bhi(hA.y);
    a[4] += aA*blo(hA.z); a[5] += aA*bhi(hA.z);
    a[6] += aA*blo(hA.w); a[7] += aA*bhi(hA.w);
  }
  // head mean
  #pragma unroll
  for (int d = 16; d < 64; d <<= 1)
    #pragma unroll
    for (int j = 0; j < 8; j++) a[j] += __shfl_xor(a[j], d);
  if (lane < 16){
    int c = lane*8;
    float4 o0 = make_float4(0.25f*a[0]+bias[c+0], 0.25f*a[1]+bias[c+1],
                            0.25f*a[2]+bias[c+2], 0.25f*a[3]+bias[c+3]);
    float4 o1 = make_float4(0.25f*a[4]+bias[c+4], 0.25f*a[5]+bias[c+5],
                            0.25f*a[6]+bias[c+6], 0.25f*a[7]+bias[c+7]);
    *(float4*)(Y + (size_t)gw*H_ + c)     = o0;
    *(float4*)(Y + (size_t)gw*H_ + c + 4) = o1;
  }
}

// ---------------- LayerNorm + ReLU: read f32, write bf16 (next layer's input) ----------------
__global__ __launch_bounds__(256) void k_lnrelu(const float* __restrict__ Y,
    const float* __restrict__ g, const float* __restrict__ bb, unsigned short* __restrict__ Xb){
  int gw = (blockIdx.x*blockDim.x + threadIdx.x) >> 6;
  int lane = threadIdx.x & 63;
  float2 v = *(const float2*)(Y + (size_t)gw*H_ + lane*2);
  float sum = v.x + v.y;
  #pragma unroll
  for (int d = 1; d < 64; d <<= 1) sum += __shfl_xor(sum, d);
  float mu = sum * (1.f/H_);
  float dx = v.x - mu, dy = v.y - mu;
  float vs = dx*dx + dy*dy;
  #pragma unroll
  for (int d = 1; d < 64; d <<= 1) vs += __shfl_xor(vs, d);
  float inv = rsqrtf(vs*(1.f/H_) + 1e-5f);
  float2 gv = *(const float2*)(g + lane*2);
  float2 bv = *(const float2*)(bb + lane*2);
  float ox = fmaxf(dx*inv*gv.x + bv.x, 0.f);
  float oy = fmaxf(dy*inv*gv.y + bv.y, 0.f);
  unsigned int o = ((unsigned int)f2b(oy) << 16) | (unsigned int)f2b(ox);
  *(unsigned int*)(Xb + (size_t)gw*H_ + lane*2) = o;
}

extern "C" void kernel_launch(void* const* d_in, const int* in_sizes, int n_in,
                              void* d_out, int out_size, void* d_ws, size_t ws_size,
                              hipStream_t stream){
  const float* x0   = (const float*)d_in[0];
  const int*   srcI = (const int*)d_in[1];
  const int*   tgtI = (const int*)d_in[2];
  const float* Wl[3]  = {(const float*)d_in[3], (const float*)d_in[7],  (const float*)d_in[11]};
  const float* asl[3] = {(const float*)d_in[4], (const float*)d_in[8],  (const float*)d_in[12]};
  const float* adl[3] = {(const float*)d_in[5], (const float*)d_in[9],  (const float*)d_in[13]};
  const float* bl[3]  = {(const float*)d_in[6], (const float*)d_in[10], (const float*)d_in[14]};
  const float* lng[2] = {(const float*)d_in[15], (const float*)d_in[17]};
  const float* lnb[2] = {(const float*)d_in[16], (const float*)d_in[18]};

  char* p = (char*)d_ws;
  auto carve = [&](size_t bytes) -> void* {
    void* r = (void*)p; p += (bytes + 255) & ~(size_t)255; return r;
  };
  int*   off    = (int*)carve((size_t)B_*(N_+1)*4);
  int*   cnt    = (int*)carve((size_t)B_*N_*4);
  int*   cursor = (int*)carve((size_t)B_*N_*4);
  int*   csr    = (int*)carve((size_t)B_*E_*4);
  float* es     = (float*)carve((size_t)B_*N_*HEADS_*4);
  float* ed     = (float*)carve((size_t)B_*N_*HEADS_*4);
  float* was    = (float*)carve((size_t)H_*HEADS_*4);
  float* wad    = (float*)carve((size_t)H_*HEADS_*4);
  unsigned short* hbuf = (unsigned short*)carve((size_t)NROWS*HH_*2);
  unsigned short* xbf  = (unsigned short*)carve((size_t)NROWS*H_*2);
  unsigned short* wtb  = (unsigned short*)carve((size_t)HH_*H_*2);
  float* tbuf   = (float*)carve((size_t)NROWS*H_*4);

  hipMemsetAsync(cnt, 0, (size_t)B_*N_*4, stream);
  k_count  <<<dim3(E_/256, B_), 256, 0, stream>>>(tgtI, cnt);
  k_scan   <<<B_, 1024, 0, stream>>>(cnt, off, cursor);
  k_scatter<<<dim3(E_/256, B_), 256, 0, stream>>>(srcI, tgtI, cursor, csr);
  k_cast   <<<NROWS*H_/4/256, 256, 0, stream>>>(x0, xbf);

  for (int l = 0; l < 3; ++l){
    k_wa    <<<2, 256, 0, stream>>>(Wl[l], asl[l], adl[l], was, wad);
    k_wprep <<<HH_*H_/256, 256, 0, stream>>>(Wl[l], wtb);
    k_logits<<<NROWS/4, 256, 0, stream>>>(xbf, was, wad, es, ed);
    k_gemm_mfma<<<dim3(NROWS/64, HH_/64), 256, 0, stream>>>(xbf, wtb, hbuf);
    float* yout = (l == 2) ? (float*)d_out : tbuf;
    k_aggregate<<<NROWS/4, 256, 0, stream>>>(hbuf, es, ed, off, csr, bl[l], yout);
    if (l < 2){
      k_lnrelu<<<NROWS/4, 256, 0, stream>>>(tbuf, lng[l], lnb[l], xbf);
    }
  }
}

// Round 3
// 488.593 us; speedup vs baseline: 1.8655x; 1.0607x over previous
//
#include <hip/hip_runtime.h>
#include <hip/hip_bf16.h>
#include <cstdint>
#include <cstddef>

#define B_ 4
#define N_ 10000
#define E_ 160000
#define H_ 128
#define HEADS_ 4
#define HH_ 512
#define NROWS (B_*N_)

typedef __attribute__((ext_vector_type(8))) short bf16x8;
typedef __attribute__((ext_vector_type(4))) float f32x4;
typedef __attribute__((ext_vector_type(2))) float f32x2;

__device__ __forceinline__ float lrelu(float x){ return x > 0.f ? x : 0.2f*x; }
__device__ __forceinline__ unsigned short f2b(float f){
  unsigned int u = __builtin_bit_cast(unsigned int, f);
  unsigned int r = (u + 0x7fffu + ((u >> 16) & 1u)) >> 16;
  return (unsigned short)r;
}
__device__ __forceinline__ float blo(unsigned int u){ return __builtin_bit_cast(float, u << 16); }
__device__ __forceinline__ float bhi(unsigned int u){ return __builtin_bit_cast(float, u & 0xffff0000u); }

// ---------------- CSR build ----------------
__global__ void k_count(const int* __restrict__ tgt, int* __restrict__ cnt){
  int e = blockIdx.x*blockDim.x + threadIdx.x;
  int b = blockIdx.y;
  int t = tgt[(size_t)b*E_ + e];
  atomicAdd(&cnt[b*N_ + t], 1);
}

__global__ void k_scan(const int* __restrict__ cnt, int* __restrict__ off, int* __restrict__ cursor){
  int b = blockIdx.x;
  __shared__ int wsum[16];
  __shared__ int carry_s;
  int lane = threadIdx.x & 63, wid = threadIdx.x >> 6;
  if (threadIdx.x == 0){ carry_s = 0; off[b*(N_+1)] = 0; }
  __syncthreads();
  for (int base = 0; base < N_; base += 1024){
    int i = base + threadIdx.x;
    int v = (i < N_) ? cnt[b*N_ + i] : 0;
    int x = v;
    #pragma unroll
    for (int d = 1; d < 64; d <<= 1){
      int y = __shfl_up(x, d);
      if (lane >= d) x += y;
    }
    if (lane == 63) wsum[wid] = x;
    __syncthreads();
    if (wid == 0 && lane < 16){
      int w = wsum[lane];
      #pragma unroll
      for (int d = 1; d < 16; d <<= 1){
        int y = __shfl_up(w, d, 16);
        if (lane >= d) w += y;
      }
      wsum[lane] = w;
    }
    __syncthreads();
    int excl = (wid ? wsum[wid-1] : 0) + carry_s;
    if (i < N_){
      int inc = x + excl;
      off[b*(N_+1) + i + 1] = inc;
      cursor[b*N_ + i] = inc - v;
    }
    __syncthreads();
    if (threadIdx.x == 0) carry_s += wsum[15];
    __syncthreads();
  }
}

__global__ void k_scatter(const int* __restrict__ src, const int* __restrict__ tgt,
                          int* __restrict__ cursor, int* __restrict__ csr){
  int e = blockIdx.x*blockDim.x + threadIdx.x;
  int b = blockIdx.y;
  int t = tgt[(size_t)b*E_ + e];
  int pos = atomicAdd(&cursor[b*N_ + t], 1);
  csr[(size_t)b*E_ + pos] = src[(size_t)b*E_ + e];
}

// ---------------- prep: Wa tables + W transpose/cast, all 3 layers ----------------
__global__ void k_prep(const float* __restrict__ W0, const float* __restrict__ W1, const float* __restrict__ W2,
                       const float* __restrict__ as0, const float* __restrict__ as1, const float* __restrict__ as2,
                       const float* __restrict__ ad0, const float* __restrict__ ad1, const float* __restrict__ ad2,
                       float* __restrict__ wasA, float* __restrict__ wadA, unsigned short* __restrict__ wtA){
  int l = blockIdx.y;
  const float* W   = (l==0)?W0:(l==1)?W1:W2;
  const float* asp = (l==0)?as0:(l==1)?as1:as2;
  const float* adp = (l==0)?ad0:(l==1)?ad1:ad2;
  if (blockIdx.x < 256){
    int i = blockIdx.x*256 + threadIdx.x;     // i = c*H_ + k
    int c = i >> 7, k = i & 127;
    wtA[(size_t)l*HH_*H_ + i] = f2b(W[(size_t)k*HH_ + c]);
  } else {
    int j = (blockIdx.x - 256)*256 + threadIdx.x;   // j = k*4 + h
    if (j < H_*HEADS_){
      int k = j >> 2, h = j & 3;
      const float* wrow = W + (size_t)k*HH_ + h*H_;
      const float* asr = asp + h*H_;
      const float* adr = adp + h*H_;
      float ss = 0.f, sd = 0.f;
      for (int c = 0; c < H_; ++c){ float w = wrow[c]; ss += w*asr[c]; sd += w*adr[c]; }
      wasA[l*HH_ + j] = ss; wadA[l*HH_ + j] = sd;
    }
  }
}

// ---------------- layer-1: cast x->bf16 + logits (one wave per row) ----------------
__global__ __launch_bounds__(256) void k_cast_logits(const float* __restrict__ X,
    const float* __restrict__ was, const float* __restrict__ wad,
    unsigned short* __restrict__ Xb, float* __restrict__ es, float* __restrict__ ed){
  int gw = (blockIdx.x*blockDim.x + threadIdx.x) >> 6;
  int lane = threadIdx.x & 63;
  float2 v = *(const float2*)(X + (size_t)gw*H_ + lane*2);
  unsigned int o = ((unsigned int)f2b(v.y) << 16) | (unsigned int)f2b(v.x);
  *(unsigned int*)(Xb + (size_t)gw*H_ + lane*2) = o;
  int c = lane*2;
  const f32x4* w4 = (const f32x4*)was;
  const f32x4* d4 = (const f32x4*)wad;
  f32x4 se = v.x*w4[c] + v.y*w4[c+1];
  f32x4 de = v.x*d4[c] + v.y*d4[c+1];
  #pragma unroll
  for (int d = 1; d < 64; d <<= 1){
    se.x += __shfl_xor(se.x,d); se.y += __shfl_xor(se.y,d);
    se.z += __shfl_xor(se.z,d); se.w += __shfl_xor(se.w,d);
    de.x += __shfl_xor(de.x,d); de.y += __shfl_xor(de.y,d);
    de.z += __shfl_xor(de.z,d); de.w += __shfl_xor(de.w,d);
  }
  if (lane == 0){
    *(float4*)(es + (size_t)gw*4) = make_float4(se.x, se.y, se.z, se.w);
    *(float4*)(ed + (size_t)gw*4) = make_float4(de.x, de.y, de.z, de.w);
  }
}

// ---------------- h = x @ W  (bf16 MFMA 16x16x32; 64x64 tile) ----------------
__global__ __launch_bounds__(256) void k_gemm_mfma(const unsigned short* __restrict__ Xb,
    const unsigned short* __restrict__ Wt, unsigned short* __restrict__ Hb){
  __shared__ unsigned short xs[64*128];
  __shared__ unsigned short ws[64*128];
  int row0 = blockIdx.x * 64, col0 = blockIdx.y * 64;
  int tid = threadIdx.x;
  int ch = tid & 15, r0 = tid >> 4;
  #pragma unroll
  for (int p = 0; p < 4; ++p){
    int r = r0 + p*16;
    int sc = ch ^ (r & 7);
    *(uint4*)(&xs[r*128 + sc*8]) = *(const uint4*)(Xb + (size_t)(row0 + r)*H_ + ch*8);
    *(uint4*)(&ws[r*128 + sc*8]) = *(const uint4*)(Wt + (size_t)(col0 + r)*H_ + ch*8);
  }
  __syncthreads();
  int w = tid >> 6, l = tid & 63;
  int lr = l & 15, q = l >> 4;
  f32x4 z = {0.f, 0.f, 0.f, 0.f};
  f32x4 acc[4] = {z, z, z, z};
  int arow = w*16 + lr;
  #pragma unroll
  for (int kf = 0; kf < 4; ++kf){
    int bch = kf*4 + q;
    bf16x8 a = *(const bf16x8*)(&xs[arow*128 + (bch ^ (arow & 7))*8]);
    #pragma unroll
    for (int cf = 0; cf < 4; ++cf){
      int brow = cf*16 + lr;
      bf16x8 bfr = *(const bf16x8*)(&ws[brow*128 + (bch ^ (brow & 7))*8]);
      acc[cf] = __builtin_amdgcn_mfma_f32_16x16x32_bf16(a, bfr, acc[cf], 0, 0, 0);
    }
  }
  #pragma unroll
  for (int cf = 0; cf < 4; ++cf){
    #pragma unroll
    for (int rg = 0; rg < 4; ++rg){
      int row = row0 + w*16 + q*4 + rg;
      int col = col0 + cf*16 + lr;
      Hb[(size_t)row*HH_ + col] = f2b(acc[cf][rg]);
    }
  }
}

// ---------------- aggregate + (LN+ReLU + next-layer logits | final write) ----------------
template<bool FINAL>
__global__ __launch_bounds__(256) void k_aggregate(
    const unsigned short* __restrict__ Hb,
    const float* __restrict__ es, const float* __restrict__ ed,
    const int* __restrict__ off, const int* __restrict__ csr,
    const float* __restrict__ bias,
    const float* __restrict__ wasN, const float* __restrict__ wadN,
    const float* __restrict__ lng, const float* __restrict__ lnb,
    float* __restrict__ Yout, unsigned short* __restrict__ Xbout,
    float* __restrict__ esN, float* __restrict__ edN)
{
  __shared__ float alpha_s[4][64][4];
  __shared__ int   srcn_s[4][64];
  __shared__ float orow_s[4][128];
  int wv = threadIdx.x >> 6, lane = threadIdx.x & 63;
  int gw = blockIdx.x*4 + wv;
  int b = gw / N_, t = gw - b*N_;
  const float4 edv = *(const float4*)(ed + (size_t)gw*4);
  int start = off[b*(N_+1) + t];
  int deg = off[b*(N_+1) + t + 1] - start;
  int total = deg + 1;                       // + implicit self-loop
  const int* lst = csr + (size_t)b*E_ + start;
  const float* esb = es + (size_t)b*N_*4;
  int head = lane >> 4;
  int cb = head*H_ + (lane & 15)*8;
  const unsigned short* hbase = Hb + (size_t)b*N_*HH_;
  f32x2 zz = {0.f, 0.f};
  f32x2 ac[4] = {zz, zz, zz, zz};

  if (total <= 64){
    // ---- fast path: one lane per edge ----
    bool valid = lane < total;
    int srcn = (lane < deg) ? lst[lane] : t;
    srcn_s[wv][lane] = srcn;
    float4 ev = *(const float4*)(esb + (size_t)srcn*4);
    float e0 = valid ? lrelu(ev.x + edv.x) : -1e30f;
    float e1 = valid ? lrelu(ev.y + edv.y) : -1e30f;
    float e2 = valid ? lrelu(ev.z + edv.z) : -1e30f;
    float e3 = valid ? lrelu(ev.w + edv.w) : -1e30f;
    float M0 = e0, M1 = e1, M2 = e2, M3 = e3;
    #pragma unroll
    for (int d = 1; d < 64; d <<= 1){
      M0 = fmaxf(M0, __shfl_xor(M0, d)); M1 = fmaxf(M1, __shfl_xor(M1, d));
      M2 = fmaxf(M2, __shfl_xor(M2, d)); M3 = fmaxf(M3, __shfl_xor(M3, d));
    }
    float p0 = valid ? __expf(e0 - M0) : 0.f;
    float p1 = valid ? __expf(e1 - M1) : 0.f;
    float p2 = valid ? __expf(e2 - M2) : 0.f;
    float p3 = valid ? __expf(e3 - M3) : 0.f;
    float S0 = p0, S1 = p1, S2 = p2, S3 = p3;
    #pragma unroll
    for (int d = 1; d < 64; d <<= 1){
      S0 += __shfl_xor(S0, d); S1 += __shfl_xor(S1, d);
      S2 += __shfl_xor(S2, d); S3 += __shfl_xor(S3, d);
    }
    *(float4*)(&alpha_s[wv][lane][0]) = make_float4(p0/S0, p1/S1, p2/S2, p3/S3);
    __builtin_amdgcn_wave_barrier();

    int i = 0;
    for (; i + 2 <= total; i += 2){
      int sA = srcn_s[wv][i];
      int sB = srcn_s[wv][i+1];
      float aA = alpha_s[wv][i][head];
      float aB = alpha_s[wv][i+1][head];
      uint4 hA = *(const uint4*)(hbase + (size_t)sA*HH_ + cb);
      uint4 hB = *(const uint4*)(hbase + (size_t)sB*HH_ + cb);
      f32x2 vA = {aA, aA}, vB = {aB, aB};
      ac[0] += vA * (f32x2){blo(hA.x), bhi(hA.x)};
      ac[1] += vA * (f32x2){blo(hA.y), bhi(hA.y)};
      ac[2] += vA * (f32x2){blo(hA.z), bhi(hA.z)};
      ac[3] += vA * (f32x2){blo(hA.w), bhi(hA.w)};
      ac[0] += vB * (f32x2){blo(hB.x), bhi(hB.x)};
      ac[1] += vB * (f32x2){blo(hB.y), bhi(hB.y)};
      ac[2] += vB * (f32x2){blo(hB.z), bhi(hB.z)};
      ac[3] += vB * (f32x2){blo(hB.w), bhi(hB.w)};
    }
    if (i < total){
      int sA = srcn_s[wv][i];
      float aA = alpha_s[wv][i][head];
      uint4 hA = *(const uint4*)(hbase + (size_t)sA*HH_ + cb);
      f32x2 vA = {aA, aA};
      ac[0] += vA * (f32x2){blo(hA.x), bhi(hA.x)};
      ac[1] += vA * (f32x2){blo(hA.y), bhi(hA.y)};
      ac[2] += vA * (f32x2){blo(hA.z), bhi(hA.z)};
      ac[3] += vA * (f32x2){blo(hA.w), bhi(hA.w)};
    }
  } else {
    // ---- slow path (deg >= 64): online softmax + inline alpha ----
    float m0=-1e30f, m1=-1e30f, m2=-1e30f, m3=-1e30f;
    float s0=0.f, s1=0.f, s2=0.f, s3=0.f;
    for (int i2 = lane; i2 <= deg; i2 += 64){
      int srcn = (i2 < deg) ? lst[i2] : t;
      float4 ev = *(const float4*)(esb + (size_t)srcn*4);
      float e0 = lrelu(ev.x + edv.x);
      float e1 = lrelu(ev.y + edv.y);
      float e2 = lrelu(ev.z + edv.z);
      float e3 = lrelu(ev.w + edv.w);
      float nm;
      nm = fmaxf(m0, e0); s0 = s0*__expf(m0-nm) + __expf(e0-nm); m0 = nm;
      nm = fmaxf(m1, e1); s1 = s1*__expf(m1-nm) + __expf(e1-nm); m1 = nm;
      nm = fmaxf(m2, e2); s2 = s2*__expf(m2-nm) + __expf(e2-nm); m2 = nm;
      nm = fmaxf(m3, e3); s3 = s3*__expf(m3-nm) + __expf(e3-nm); m3 = nm;
    }
    #pragma unroll
    for (int d = 1; d < 64; d <<= 1){
      float om, os, nm;
      om = __shfl_xor(m0, d); os = __shfl_xor(s0, d); nm = fmaxf(m0, om);
      s0 = s0*__expf(m0-nm) + os*__expf(om-nm); m0 = nm;
      om = __shfl_xor(m1, d); os = __shfl_xor(s1, d); nm = fmaxf(m1, om);
      s1 = s1*__expf(m1-nm) + os*__expf(om-nm); m1 = nm;
      om = __shfl_xor(m2, d); os = __shfl_xor(s2, d); nm = fmaxf(m2, om);
      s2 = s2*__expf(m2-nm) + os*__expf(om-nm); m2 = nm;
      om = __shfl_xor(m3, d); os = __shfl_xor(s3, d); nm = fmaxf(m3, om);
      s3 = s3*__expf(m3-nm) + os*__expf(om-nm); m3 = nm;
    }
    float mh, sh, edh;
    if      (head == 0){ mh = m0; sh = s0; edh = edv.x; }
    else if (head == 1){ mh = m1; sh = s1; edh = edv.y; }
    else if (head == 2){ mh = m2; sh = s2; edh = edv.z; }
    else               { mh = m3; sh = s3; edh = edv.w; }
    float rh = 1.0f / sh;
    for (int i2 = 0; i2 < total; ++i2){
      int srcn = (i2 < deg) ? lst[i2] : t;
      float eh = esb[(size_t)srcn*4 + head];
      float al = __expf(lrelu(eh + edh) - mh) * rh;
      uint4 hA = *(const uint4*)(hbase + (size_t)srcn*HH_ + cb);
      f32x2 vA = {al, al};
      ac[0] += vA * (f32x2){blo(hA.x), bhi(hA.x)};
      ac[1] += vA * (f32x2){blo(hA.y), bhi(hA.y)};
      ac[2] += vA * (f32x2){blo(hA.z), bhi(hA.z)};
      ac[3] += vA * (f32x2){blo(hA.w), bhi(hA.w)};
    }
  }

  // ---- epilogue: head mean ----
  float a[8] = {ac[0].x, ac[0].y, ac[1].x, ac[1].y, ac[2].x, ac[2].y, ac[3].x, ac[3].y};
  #pragma unroll
  for (int d = 16; d < 64; d <<= 1)
    #pragma unroll
    for (int j = 0; j < 8; j++) a[j] += __shfl_xor(a[j], d);

  int c = (lane & 15)*8;
  if (FINAL){
    if (lane < 16){
      float4 o0 = make_float4(0.25f*a[0]+bias[c+0], 0.25f*a[1]+bias[c+1],
                              0.25f*a[2]+bias[c+2], 0.25f*a[3]+bias[c+3]);
      float4 o1 = make_float4(0.25f*a[4]+bias[c+4], 0.25f*a[5]+bias[c+5],
                              0.25f*a[6]+bias[c+6], 0.25f*a[7]+bias[c+7]);
      *(float4*)(Yout + (size_t)gw*H_ + c)     = o0;
      *(float4*)(Yout + (size_t)gw*H_ + c + 4) = o1;
    }
  } else {
    float o[8];
    #pragma unroll
    for (int j = 0; j < 8; j++) o[j] = 0.25f*a[j] + bias[c+j];
    // LayerNorm across lanes 0..15 (each holds 8 channels)
    float ss = 0.f;
    #pragma unroll
    for (int j = 0; j < 8; j++) ss += o[j];
    #pragma unroll
    for (int d = 1; d < 16; d <<= 1) ss += __shfl_xor(ss, d);
    float mu = ss * (1.f/H_);
    float vv = 0.f;
    #pragma unroll
    for (int j = 0; j < 8; j++){ float dx = o[j]-mu; vv += dx*dx; }
    #pragma unroll
    for (int d = 1; d < 16; d <<= 1) vv += __shfl_xor(vv, d);
    float inv = rsqrtf(vv*(1.f/H_) + 1e-5f);
    float4 g0 = *(const float4*)(lng + c), g1 = *(const float4*)(lng + c + 4);
    float4 b0 = *(const float4*)(lnb + c), b1 = *(const float4*)(lnb + c + 4);
    float gg[8] = {g0.x,g0.y,g0.z,g0.w,g1.x,g1.y,g1.z,g1.w};
    float bb[8] = {b0.x,b0.y,b0.z,b0.w,b1.x,b1.y,b1.z,b1.w};
    float oo[8];
    #pragma unroll
    for (int j = 0; j < 8; j++) oo[j] = fmaxf((o[j]-mu)*inv*gg[j] + bb[j], 0.f);
    if (lane < 16){
      uint4 up;
      up.x = ((unsigned int)f2b(oo[1]) << 16) | f2b(oo[0]);
      up.y = ((unsigned int)f2b(oo[3]) << 16) | f2b(oo[2]);
      up.z = ((unsigned int)f2b(oo[5]) << 16) | f2b(oo[4]);
      up.w = ((unsigned int)f2b(oo[7]) << 16) | f2b(oo[6]);
      *(uint4*)(Xbout + (size_t)gw*H_ + lane*8) = up;
      *(float4*)(&orow_s[wv][c])     = make_float4(oo[0], oo[1], oo[2], oo[3]);
      *(float4*)(&orow_s[wv][c + 4]) = make_float4(oo[4], oo[5], oo[6], oo[7]);
    }
    __builtin_amdgcn_wave_barrier();
    // next-layer logits: all 64 lanes, lane = (head, 8 channels)
    float pe = 0.f, pd = 0.f;
    #pragma unroll
    for (int j = 0; j < 8; j++){
      float xv = orow_s[wv][c + j];
      pe += xv * wasN[(c + j)*4 + head];
      pd += xv * wadN[(c + j)*4 + head];
    }
    #pragma unroll
    for (int d = 1; d < 16; d <<= 1){ pe += __shfl_xor(pe, d); pd += __shfl_xor(pd, d); }
    if ((lane & 15) == 0){
      esN[(size_t)gw*4 + head] = pe;
      edN[(size_t)gw*4 + head] = pd;
    }
  }
}

extern "C" void kernel_launch(void* const* d_in, const int* in_sizes, int n_in,
                              void* d_out, int out_size, void* d_ws, size_t ws_size,
                              hipStream_t stream){
  const float* x0   = (const float*)d_in[0];
  const int*   srcI = (const int*)d_in[1];
  const int*   tgtI = (const int*)d_in[2];
  const float* Wl[3]  = {(const float*)d_in[3], (const float*)d_in[7],  (const float*)d_in[11]};
  const float* asl[3] = {(const float*)d_in[4], (const float*)d_in[8],  (const float*)d_in[12]};
  const float* adl[3] = {(const float*)d_in[5], (const float*)d_in[9],  (const float*)d_in[13]};
  const float* bl[3]  = {(const float*)d_in[6], (const float*)d_in[10], (const float*)d_in[14]};
  const float* lng[2] = {(const float*)d_in[15], (const float*)d_in[17]};
  const float* lnb[2] = {(const float*)d_in[16], (const float*)d_in[18]};

  char* p = (char*)d_ws;
  auto carve = [&](size_t bytes) -> void* {
    void* r = (void*)p; p += (bytes + 255) & ~(size_t)255; return r;
  };
  int*   off    = (int*)carve((size_t)B_*(N_+1)*4);
  int*   cnt    = (int*)carve((size_t)B_*N_*4);
  int*   cursor = (int*)carve((size_t)B_*N_*4);
  int*   csr    = (int*)carve((size_t)B_*E_*4);
  float* es2[2] = {(float*)carve((size_t)NROWS*4*4), (float*)carve((size_t)NROWS*4*4)};
  float* ed2[2] = {(float*)carve((size_t)NROWS*4*4), (float*)carve((size_t)NROWS*4*4)};
  float* wasA   = (float*)carve((size_t)3*HH_*4);
  float* wadA   = (float*)carve((size_t)3*HH_*4);
  unsigned short* wtA  = (unsigned short*)carve((size_t)3*HH_*H_*2);
  unsigned short* hbuf = (unsigned short*)carve((size_t)NROWS*HH_*2);
  unsigned short* xbf  = (unsigned short*)carve((size_t)NROWS*H_*2);

  hipMemsetAsync(cnt, 0, (size_t)B_*N_*4, stream);
  k_count  <<<dim3(E_/256, B_), 256, 0, stream>>>(tgtI, cnt);
  k_scan   <<<B_, 1024, 0, stream>>>(cnt, off, cursor);
  k_scatter<<<dim3(E_/256, B_), 256, 0, stream>>>(srcI, tgtI, cursor, csr);
  k_prep   <<<dim3(258, 3), 256, 0, stream>>>(Wl[0], Wl[1], Wl[2],
                                              asl[0], asl[1], asl[2],
                                              adl[0], adl[1], adl[2],
                                              wasA, wadA, wtA);
  k_cast_logits<<<NROWS/4, 256, 0, stream>>>(x0, wasA, wadA, xbf, es2[0], ed2[0]);

  for (int l = 0; l < 3; ++l){
    k_gemm_mfma<<<dim3(NROWS/64, HH_/64), 256, 0, stream>>>(xbf, wtA + (size_t)l*HH_*H_, hbuf);
    int cur = l & 1, nxt = cur ^ 1;
    if (l < 2){
      k_aggregate<false><<<NROWS/4, 256, 0, stream>>>(hbuf, es2[cur], ed2[cur], off, csr, bl[l],
          wasA + (size_t)(l+1)*HH_, wadA + (size_t)(l+1)*HH_, lng[l], lnb[l],
          nullptr, xbf, es2[nxt], ed2[nxt]);
    } else {
      k_aggregate<true><<<NROWS/4, 256, 0, stream>>>(hbuf, es2[cur], ed2[cur], off, csr, bl[l],
          nullptr, nullptr, nullptr, nullptr,
          (float*)d_out, nullptr, nullptr, nullptr);
    }
  }
}

// Round 4
// 487.091 us; speedup vs baseline: 1.8713x; 1.0031x over previous
//
#include <hip/hip_runtime.h>
#include <hip/hip_bf16.h>
#include <cstdint>
#include <cstddef>

#define B_ 4
#define N_ 10000
#define E_ 160000
#define H_ 128
#define HEADS_ 4
#define HH_ 512
#define NROWS (B_*N_)

typedef __attribute__((ext_vector_type(8))) short bf16x8;
typedef __attribute__((ext_vector_type(4))) float f32x4;
typedef __attribute__((ext_vector_type(2))) float f32x2;

__device__ __forceinline__ float lrelu(float x){ return x > 0.f ? x : 0.2f*x; }
__device__ __forceinline__ unsigned short f2b(float f){
  unsigned int u = __builtin_bit_cast(unsigned int, f);
  unsigned int r = (u + 0x7fffu + ((u >> 16) & 1u)) >> 16;
  return (unsigned short)r;
}
__device__ __forceinline__ float blo(unsigned int u){ return __builtin_bit_cast(float, u << 16); }
__device__ __forceinline__ float bhi(unsigned int u){ return __builtin_bit_cast(float, u & 0xffff0000u); }

__device__ __forceinline__ void acc_row(f32x2* ac, float al, uint4 h){
  f32x2 v = {al, al};
  ac[0] += v * (f32x2){blo(h.x), bhi(h.x)};
  ac[1] += v * (f32x2){blo(h.y), bhi(h.y)};
  ac[2] += v * (f32x2){blo(h.z), bhi(h.z)};
  ac[3] += v * (f32x2){blo(h.w), bhi(h.w)};
}

// ---------------- CSR build ----------------
__global__ void k_count(const int* __restrict__ tgt, int* __restrict__ cnt){
  int e = blockIdx.x*blockDim.x + threadIdx.x;
  int b = blockIdx.y;
  int t = tgt[(size_t)b*E_ + e];
  atomicAdd(&cnt[b*N_ + t], 1);
}

__global__ void k_scan(const int* __restrict__ cnt, int* __restrict__ off, int* __restrict__ cursor){
  int b = blockIdx.x;
  __shared__ int wsum[16];
  __shared__ int carry_s;
  int lane = threadIdx.x & 63, wid = threadIdx.x >> 6;
  if (threadIdx.x == 0){ carry_s = 0; off[b*(N_+1)] = 0; }
  __syncthreads();
  for (int base = 0; base < N_; base += 1024){
    int i = base + threadIdx.x;
    int v = (i < N_) ? cnt[b*N_ + i] : 0;
    int x = v;
    #pragma unroll
    for (int d = 1; d < 64; d <<= 1){
      int y = __shfl_up(x, d);
      if (lane >= d) x += y;
    }
    if (lane == 63) wsum[wid] = x;
    __syncthreads();
    if (wid == 0 && lane < 16){
      int w = wsum[lane];
      #pragma unroll
      for (int d = 1; d < 16; d <<= 1){
        int y = __shfl_up(w, d, 16);
        if (lane >= d) w += y;
      }
      wsum[lane] = w;
    }
    __syncthreads();
    int excl = (wid ? wsum[wid-1] : 0) + carry_s;
    if (i < N_){
      int inc = x + excl;
      off[b*(N_+1) + i + 1] = inc;
      cursor[b*N_ + i] = inc - v;
    }
    __syncthreads();
    if (threadIdx.x == 0) carry_s += wsum[15];
    __syncthreads();
  }
}

__global__ void k_scatter(const int* __restrict__ src, const int* __restrict__ tgt,
                          int* __restrict__ cursor, int* __restrict__ csr){
  int e = blockIdx.x*blockDim.x + threadIdx.x;
  int b = blockIdx.y;
  int t = tgt[(size_t)b*E_ + e];
  int pos = atomicAdd(&cursor[b*N_ + t], 1);
  csr[(size_t)b*E_ + pos] = src[(size_t)b*E_ + e];
}

// ---------------- prep: Wa tables + W transpose/cast, all 3 layers ----------------
__global__ void k_prep(const float* __restrict__ W0, const float* __restrict__ W1, const float* __restrict__ W2,
                       const float* __restrict__ as0, const float* __restrict__ as1, const float* __restrict__ as2,
                       const float* __restrict__ ad0, const float* __restrict__ ad1, const float* __restrict__ ad2,
                       float* __restrict__ wasA, float* __restrict__ wadA, unsigned short* __restrict__ wtA){
  int l = blockIdx.y;
  const float* W   = (l==0)?W0:(l==1)?W1:W2;
  const float* asp = (l==0)?as0:(l==1)?as1:as2;
  const float* adp = (l==0)?ad0:(l==1)?ad1:ad2;
  if (blockIdx.x < 256){
    int i = blockIdx.x*256 + threadIdx.x;     // i = c*H_ + k
    int c = i >> 7, k = i & 127;
    wtA[(size_t)l*HH_*H_ + i] = f2b(W[(size_t)k*HH_ + c]);
  } else {
    int j = (blockIdx.x - 256)*256 + threadIdx.x;   // j = k*4 + h
    if (j < H_*HEADS_){
      int k = j >> 2, h = j & 3;
      const float* wrow = W + (size_t)k*HH_ + h*H_;
      const float* asr = asp + h*H_;
      const float* adr = adp + h*H_;
      float ss = 0.f, sd = 0.f;
      for (int c = 0; c < H_; ++c){ float w = wrow[c]; ss += w*asr[c]; sd += w*adr[c]; }
      wasA[l*HH_ + j] = ss; wadA[l*HH_ + j] = sd;
    }
  }
}

// ---------------- layer-1: cast x->bf16 + logits (one wave per row) ----------------
__global__ __launch_bounds__(256) void k_cast_logits(const float* __restrict__ X,
    const float* __restrict__ was, const float* __restrict__ wad,
    unsigned short* __restrict__ Xb, float* __restrict__ es, float* __restrict__ ed){
  int gw = (blockIdx.x*blockDim.x + threadIdx.x) >> 6;
  int lane = threadIdx.x & 63;
  float2 v = *(const float2*)(X + (size_t)gw*H_ + lane*2);
  unsigned int o = ((unsigned int)f2b(v.y) << 16) | (unsigned int)f2b(v.x);
  *(unsigned int*)(Xb + (size_t)gw*H_ + lane*2) = o;
  int c = lane*2;
  const f32x4* w4 = (const f32x4*)was;
  const f32x4* d4 = (const f32x4*)wad;
  f32x4 se = v.x*w4[c] + v.y*w4[c+1];
  f32x4 de = v.x*d4[c] + v.y*d4[c+1];
  #pragma unroll
  for (int d = 1; d < 64; d <<= 1){
    se.x += __shfl_xor(se.x,d); se.y += __shfl_xor(se.y,d);
    se.z += __shfl_xor(se.z,d); se.w += __shfl_xor(se.w,d);
    de.x += __shfl_xor(de.x,d); de.y += __shfl_xor(de.y,d);
    de.z += __shfl_xor(de.z,d); de.w += __shfl_xor(de.w,d);
  }
  if (lane == 0){
    *(float4*)(es + (size_t)gw*4) = make_float4(se.x, se.y, se.z, se.w);
    *(float4*)(ed + (size_t)gw*4) = make_float4(de.x, de.y, de.z, de.w);
  }
}

// ---------------- h = x @ W  (bf16 MFMA 16x16x32; 64x64 tile) ----------------
__global__ __launch_bounds__(256) void k_gemm_mfma(const unsigned short* __restrict__ Xb,
    const unsigned short* __restrict__ Wt, unsigned short* __restrict__ Hb){
  __shared__ unsigned short xs[64*128];
  __shared__ unsigned short ws[64*128];
  int row0 = blockIdx.x * 64, col0 = blockIdx.y * 64;
  int tid = threadIdx.x;
  int ch = tid & 15, r0 = tid >> 4;
  #pragma unroll
  for (int p = 0; p < 4; ++p){
    int r = r0 + p*16;
    int sc = ch ^ (r & 7);
    *(uint4*)(&xs[r*128 + sc*8]) = *(const uint4*)(Xb + (size_t)(row0 + r)*H_ + ch*8);
    *(uint4*)(&ws[r*128 + sc*8]) = *(const uint4*)(Wt + (size_t)(col0 + r)*H_ + ch*8);
  }
  __syncthreads();
  int w = tid >> 6, l = tid & 63;
  int lr = l & 15, q = l >> 4;
  f32x4 z = {0.f, 0.f, 0.f, 0.f};
  f32x4 acc[4] = {z, z, z, z};
  int arow = w*16 + lr;
  #pragma unroll
  for (int kf = 0; kf < 4; ++kf){
    int bch = kf*4 + q;
    bf16x8 a = *(const bf16x8*)(&xs[arow*128 + (bch ^ (arow & 7))*8]);
    #pragma unroll
    for (int cf = 0; cf < 4; ++cf){
      int brow = cf*16 + lr;
      bf16x8 bfr = *(const bf16x8*)(&ws[brow*128 + (bch ^ (brow & 7))*8]);
      acc[cf] = __builtin_amdgcn_mfma_f32_16x16x32_bf16(a, bfr, acc[cf], 0, 0, 0);
    }
  }
  #pragma unroll
  for (int cf = 0; cf < 4; ++cf){
    #pragma unroll
    for (int rg = 0; rg < 4; ++rg){
      int row = row0 + w*16 + q*4 + rg;
      int col = col0 + cf*16 + lr;
      Hb[(size_t)row*HH_ + col] = f2b(acc[cf][rg]);
    }
  }
}

// ---------------- aggregate + (LN+ReLU + next-layer logits | final write) ----------------
template<bool FINAL>
__global__ __launch_bounds__(256) void k_aggregate(
    const unsigned short* __restrict__ Hb,
    const float* __restrict__ es, const float* __restrict__ ed,
    const int* __restrict__ off, const int* __restrict__ csr,
    const float* __restrict__ bias,
    const float* __restrict__ wasN, const float* __restrict__ wadN,
    const float* __restrict__ lng, const float* __restrict__ lnb,
    float* __restrict__ Yout, unsigned short* __restrict__ Xbout,
    float* __restrict__ esN, float* __restrict__ edN)
{
  __shared__ float alpha_s[4][4][68];   // [wave][head][edge], stride 68 to spread banks
  __shared__ int   srcn_s[4][64];
  __shared__ float orow_s[4][128];
  int wv = threadIdx.x >> 6, lane = threadIdx.x & 63;
  int gw = blockIdx.x*4 + wv;
  int b = gw / N_, t = gw - b*N_;
  const float4 edv = *(const float4*)(ed + (size_t)gw*4);
  int start = off[b*(N_+1) + t];
  int deg = off[b*(N_+1) + t + 1] - start;
  int total = deg + 1;                       // + implicit self-loop
  const int* lst = csr + (size_t)b*E_ + start;
  const float* esb = es + (size_t)b*N_*4;
  int head = lane >> 4;
  int cb = head*H_ + (lane & 15)*8;
  const unsigned short* hbase = Hb + (size_t)b*N_*HH_;
  f32x2 zz = {0.f, 0.f};
  f32x2 ac[4] = {zz, zz, zz, zz};

  if (total <= 64){
    // ---- phase A: one lane per edge; padded lanes get alpha=0, src=t ----
    bool valid = lane < total;
    int srcn = (lane < deg) ? lst[lane] : t;
    srcn_s[wv][lane] = srcn;
    float4 ev = *(const float4*)(esb + (size_t)srcn*4);
    float e0 = valid ? lrelu(ev.x + edv.x) : -1e30f;
    float e1 = valid ? lrelu(ev.y + edv.y) : -1e30f;
    float e2 = valid ? lrelu(ev.z + edv.z) : -1e30f;
    float e3 = valid ? lrelu(ev.w + edv.w) : -1e30f;
    float M0 = e0, M1 = e1, M2 = e2, M3 = e3;
    #pragma unroll
    for (int d = 1; d < 64; d <<= 1){
      M0 = fmaxf(M0, __shfl_xor(M0, d)); M1 = fmaxf(M1, __shfl_xor(M1, d));
      M2 = fmaxf(M2, __shfl_xor(M2, d)); M3 = fmaxf(M3, __shfl_xor(M3, d));
    }
    float p0 = valid ? __expf(e0 - M0) : 0.f;
    float p1 = valid ? __expf(e1 - M1) : 0.f;
    float p2 = valid ? __expf(e2 - M2) : 0.f;
    float p3 = valid ? __expf(e3 - M3) : 0.f;
    float S0 = p0, S1 = p1, S2 = p2, S3 = p3;
    #pragma unroll
    for (int d = 1; d < 64; d <<= 1){
      S0 += __shfl_xor(S0, d); S1 += __shfl_xor(S1, d);
      S2 += __shfl_xor(S2, d); S3 += __shfl_xor(S3, d);
    }
    alpha_s[wv][0][lane] = p0/S0;
    alpha_s[wv][1][lane] = p1/S1;
    alpha_s[wv][2][lane] = p2/S2;
    alpha_s[wv][3][lane] = p3/S3;
    __builtin_amdgcn_wave_barrier();

    // ---- phase B: 4-edge chunks, depth-2 pipeline (8 gathers in flight) ----
    const float* alp = &alpha_s[wv][head][0];
    const int*   srp = &srcn_s[wv][0];
    auto gat = [&](int s){ return *(const uint4*)(hbase + (size_t)s*HH_ + cb); };
    int nIter = (total + 3) >> 2;
    float4 alA, alB;
    uint4 a0, a1, a2, a3, b0, b1, b2, b3;
    {
      alA = *(const float4*)(alp);
      int4 s4 = *(const int4*)(srp);
      a0 = gat(s4.x); a1 = gat(s4.y); a2 = gat(s4.z); a3 = gat(s4.w);
    }
    int it = 1;
    while (true){
      if (it == nIter){
        acc_row(ac, alA.x, a0); acc_row(ac, alA.y, a1);
        acc_row(ac, alA.z, a2); acc_row(ac, alA.w, a3);
        break;
      }
      {
        alB = *(const float4*)(alp + it*4);
        int4 s4 = *(const int4*)(srp + it*4);
        b0 = gat(s4.x); b1 = gat(s4.y); b2 = gat(s4.z); b3 = gat(s4.w);
      }
      acc_row(ac, alA.x, a0); acc_row(ac, alA.y, a1);
      acc_row(ac, alA.z, a2); acc_row(ac, alA.w, a3);
      ++it;
      if (it == nIter){
        acc_row(ac, alB.x, b0); acc_row(ac, alB.y, b1);
        acc_row(ac, alB.z, b2); acc_row(ac, alB.w, b3);
        break;
      }
      {
        alA = *(const float4*)(alp + it*4);
        int4 s4 = *(const int4*)(srp + it*4);
        a0 = gat(s4.x); a1 = gat(s4.y); a2 = gat(s4.z); a3 = gat(s4.w);
      }
      acc_row(ac, alB.x, b0); acc_row(ac, alB.y, b1);
      acc_row(ac, alB.z, b2); acc_row(ac, alB.w, b3);
      ++it;
    }
  } else {
    // ---- slow path (deg >= 64): online softmax + inline alpha ----
    float m0=-1e30f, m1=-1e30f, m2=-1e30f, m3=-1e30f;
    float s0=0.f, s1=0.f, s2=0.f, s3=0.f;
    for (int i2 = lane; i2 <= deg; i2 += 64){
      int srcn = (i2 < deg) ? lst[i2] : t;
      float4 ev = *(const float4*)(esb + (size_t)srcn*4);
      float e0 = lrelu(ev.x + edv.x);
      float e1 = lrelu(ev.y + edv.y);
      float e2 = lrelu(ev.z + edv.z);
      float e3 = lrelu(ev.w + edv.w);
      float nm;
      nm = fmaxf(m0, e0); s0 = s0*__expf(m0-nm) + __expf(e0-nm); m0 = nm;
      nm = fmaxf(m1, e1); s1 = s1*__expf(m1-nm) + __expf(e1-nm); m1 = nm;
      nm = fmaxf(m2, e2); s2 = s2*__expf(m2-nm) + __expf(e2-nm); m2 = nm;
      nm = fmaxf(m3, e3); s3 = s3*__expf(m3-nm) + __expf(e3-nm); m3 = nm;
    }
    #pragma unroll
    for (int d = 1; d < 64; d <<= 1){
      float om, os, nm;
      om = __shfl_xor(m0, d); os = __shfl_xor(s0, d); nm = fmaxf(m0, om);
      s0 = s0*__expf(m0-nm) + os*__expf(om-nm); m0 = nm;
      om = __shfl_xor(m1, d); os = __shfl_xor(s1, d); nm = fmaxf(m1, om);
      s1 = s1*__expf(m1-nm) + os*__expf(om-nm); m1 = nm;
      om = __shfl_xor(m2, d); os = __shfl_xor(s2, d); nm = fmaxf(m2, om);
      s2 = s2*__expf(m2-nm) + os*__expf(om-nm); m2 = nm;
      om = __shfl_xor(m3, d); os = __shfl_xor(s3, d); nm = fmaxf(m3, om);
      s3 = s3*__expf(m3-nm) + os*__expf(om-nm); m3 = nm;
    }
    float mh, sh, edh;
    if      (head == 0){ mh = m0; sh = s0; edh = edv.x; }
    else if (head == 1){ mh = m1; sh = s1; edh = edv.y; }
    else if (head == 2){ mh = m2; sh = s2; edh = edv.z; }
    else               { mh = m3; sh = s3; edh = edv.w; }
    float rh = 1.0f / sh;
    for (int i2 = 0; i2 < total; ++i2){
      int srcn = (i2 < deg) ? lst[i2] : t;
      float eh = esb[(size_t)srcn*4 + head];
      float al = __expf(lrelu(eh + edh) - mh) * rh;
      uint4 hA = *(const uint4*)(hbase + (size_t)srcn*HH_ + cb);
      acc_row(ac, al, hA);
    }
  }

  // ---- epilogue: head mean ----
  float a[8] = {ac[0].x, ac[0].y, ac[1].x, ac[1].y, ac[2].x, ac[2].y, ac[3].x, ac[3].y};
  #pragma unroll
  for (int d = 16; d < 64; d <<= 1)
    #pragma unroll
    for (int j = 0; j < 8; j++) a[j] += __shfl_xor(a[j], d);

  int c = (lane & 15)*8;
  if (FINAL){
    if (lane < 16){
      float4 o0 = make_float4(0.25f*a[0]+bias[c+0], 0.25f*a[1]+bias[c+1],
                              0.25f*a[2]+bias[c+2], 0.25f*a[3]+bias[c+3]);
      float4 o1 = make_float4(0.25f*a[4]+bias[c+4], 0.25f*a[5]+bias[c+5],
                              0.25f*a[6]+bias[c+6], 0.25f*a[7]+bias[c+7]);
      *(float4*)(Yout + (size_t)gw*H_ + c)     = o0;
      *(float4*)(Yout + (size_t)gw*H_ + c + 4) = o1;
    }
  } else {
    float o[8];
    #pragma unroll
    for (int j = 0; j < 8; j++) o[j] = 0.25f*a[j] + bias[c+j];
    float ss = 0.f;
    #pragma unroll
    for (int j = 0; j < 8; j++) ss += o[j];
    #pragma unroll
    for (int d = 1; d < 16; d <<= 1) ss += __shfl_xor(ss, d);
    float mu = ss * (1.f/H_);
    float vv = 0.f;
    #pragma unroll
    for (int j = 0; j < 8; j++){ float dx = o[j]-mu; vv += dx*dx; }
    #pragma unroll
    for (int d = 1; d < 16; d <<= 1) vv += __shfl_xor(vv, d);
    float inv = rsqrtf(vv*(1.f/H_) + 1e-5f);
    float4 g0 = *(const float4*)(lng + c), g1 = *(const float4*)(lng + c + 4);
    float4 b0 = *(const float4*)(lnb + c), b1 = *(const float4*)(lnb + c + 4);
    float gg[8] = {g0.x,g0.y,g0.z,g0.w,g1.x,g1.y,g1.z,g1.w};
    float bb[8] = {b0.x,b0.y,b0.z,b0.w,b1.x,b1.y,b1.z,b1.w};
    float oo[8];
    #pragma unroll
    for (int j = 0; j < 8; j++) oo[j] = fmaxf((o[j]-mu)*inv*gg[j] + bb[j], 0.f);
    if (lane < 16){
      uint4 up;
      up.x = ((unsigned int)f2b(oo[1]) << 16) | f2b(oo[0]);
      up.y = ((unsigned int)f2b(oo[3]) << 16) | f2b(oo[2]);
      up.z = ((unsigned int)f2b(oo[5]) << 16) | f2b(oo[4]);
      up.w = ((unsigned int)f2b(oo[7]) << 16) | f2b(oo[6]);
      *(uint4*)(Xbout + (size_t)gw*H_ + lane*8) = up;
      *(float4*)(&orow_s[wv][c])     = make_float4(oo[0], oo[1], oo[2], oo[3]);
      *(float4*)(&orow_s[wv][c + 4]) = make_float4(oo[4], oo[5], oo[6], oo[7]);
    }
    __builtin_amdgcn_wave_barrier();
    float pe = 0.f, pd = 0.f;
    #pragma unroll
    for (int j = 0; j < 8; j++){
      float xv = orow_s[wv][c + j];
      pe += xv * wasN[(c + j)*4 + head];
      pd += xv * wadN[(c + j)*4 + head];
    }
    #pragma unroll
    for (int d = 1; d < 16; d <<= 1){ pe += __shfl_xor(pe, d); pd += __shfl_xor(pd, d); }
    if ((lane & 15) == 0){
      esN[(size_t)gw*4 + head] = pe;
      edN[(size_t)gw*4 + head] = pd;
    }
  }
}

extern "C" void kernel_launch(void* const* d_in, const int* in_sizes, int n_in,
                              void* d_out, int out_size, void* d_ws, size_t ws_size,
                              hipStream_t stream){
  const float* x0   = (const float*)d_in[0];
  const int*   srcI = (const int*)d_in[1];
  const int*   tgtI = (const int*)d_in[2];
  const float* Wl[3]  = {(const float*)d_in[3], (const float*)d_in[7],  (const float*)d_in[11]};
  const float* asl[3] = {(const float*)d_in[4], (const float*)d_in[8],  (const float*)d_in[12]};
  const float* adl[3] = {(const float*)d_in[5], (const float*)d_in[9],  (const float*)d_in[13]};
  const float* bl[3]  = {(const float*)d_in[6], (const float*)d_in[10], (const float*)d_in[14]};
  const float* lng[2] = {(const float*)d_in[15], (const float*)d_in[17]};
  const float* lnb[2] = {(const float*)d_in[16], (const float*)d_in[18]};

  char* p = (char*)d_ws;
  auto carve = [&](size_t bytes) -> void* {
    void* r = (void*)p; p += (bytes + 255) & ~(size_t)255; return r;
  };
  int*   off    = (int*)carve((size_t)B_*(N_+1)*4);
  int*   cnt    = (int*)carve((size_t)B_*N_*4);
  int*   cursor = (int*)carve((size_t)B_*N_*4);
  int*   csr    = (int*)carve((size_t)B_*E_*4);
  float* es2[2] = {(float*)carve((size_t)NROWS*4*4), (float*)carve((size_t)NROWS*4*4)};
  float* ed2[2] = {(float*)carve((size_t)NROWS*4*4), (float*)carve((size_t)NROWS*4*4)};
  float* wasA   = (float*)carve((size_t)3*HH_*4);
  float* wadA   = (float*)carve((size_t)3*HH_*4);
  unsigned short* wtA  = (unsigned short*)carve((size_t)3*HH_*H_*2);
  unsigned short* hbuf = (unsigned short*)carve((size_t)NROWS*HH_*2);
  unsigned short* xbf  = (unsigned short*)carve((size_t)NROWS*H_*2);

  hipMemsetAsync(cnt, 0, (size_t)B_*N_*4, stream);
  k_count  <<<dim3(E_/256, B_), 256, 0, stream>>>(tgtI, cnt);
  k_scan   <<<B_, 1024, 0, stream>>>(cnt, off, cursor);
  k_scatter<<<dim3(E_/256, B_), 256, 0, stream>>>(srcI, tgtI, cursor, csr);
  k_prep   <<<dim3(258, 3), 256, 0, stream>>>(Wl[0], Wl[1], Wl[2],
                                              asl[0], asl[1], asl[2],
                                              adl[0], adl[1], adl[2],
                                              wasA, wadA, wtA);
  k_cast_logits<<<NROWS/4, 256, 0, stream>>>(x0, wasA, wadA, xbf, es2[0], ed2[0]);

  for (int l = 0; l < 3; ++l){
    k_gemm_mfma<<<dim3(NROWS/64, HH_/64), 256, 0, stream>>>(xbf, wtA + (size_t)l*HH_*H_, hbuf);
    int cur = l & 1, nxt = cur ^ 1;
    if (l < 2){
      k_aggregate<false><<<NROWS/4, 256, 0, stream>>>(hbuf, es2[cur], ed2[cur], off, csr, bl[l],
          wasA + (size_t)(l+1)*HH_, wadA + (size_t)(l+1)*HH_, lng[l], lnb[l],
          nullptr, xbf, es2[nxt], ed2[nxt]);
    } else {
      k_aggregate<true><<<NROWS/4, 256, 0, stream>>>(hbuf, es2[cur], ed2[cur], off, csr, bl[l],
          nullptr, nullptr, nullptr, nullptr,
          (float*)d_out, nullptr, nullptr, nullptr);
    }
  }
}

// Round 5
// 473.031 us; speedup vs baseline: 1.9269x; 1.0297x over previous
//
#include <hip/hip_runtime.h>
#include <hip/hip_bf16.h>
#include <cstdint>
#include <cstddef>

#define B_ 4
#define N_ 10000
#define E_ 160000
#define H_ 128
#define HEADS_ 4
#define HH_ 512
#define NROWS (B_*N_)

typedef __attribute__((ext_vector_type(8))) short bf16x8;
typedef __attribute__((ext_vector_type(4))) float f32x4;
typedef __attribute__((ext_vector_type(2))) float f32x2;

__device__ __forceinline__ float lrelu(float x){ return x > 0.f ? x : 0.2f*x; }
__device__ __forceinline__ unsigned short f2b(float f){
  unsigned int u = __builtin_bit_cast(unsigned int, f);
  unsigned int r = (u + 0x7fffu + ((u >> 16) & 1u)) >> 16;
  return (unsigned short)r;
}
__device__ __forceinline__ float blo(unsigned int u){ return __builtin_bit_cast(float, u << 16); }
__device__ __forceinline__ float bhi(unsigned int u){ return __builtin_bit_cast(float, u & 0xffff0000u); }

__device__ __forceinline__ void acc_row(f32x2* ac, float al, uint4 h){
  f32x2 v = {al, al};
  ac[0] += v * (f32x2){blo(h.x), bhi(h.x)};
  ac[1] += v * (f32x2){blo(h.y), bhi(h.y)};
  ac[2] += v * (f32x2){blo(h.z), bhi(h.z)};
  ac[3] += v * (f32x2){blo(h.w), bhi(h.w)};
}

// ---------------- CSR build ----------------
__global__ void k_count(const int* __restrict__ tgt, int* __restrict__ cnt){
  int e = blockIdx.x*blockDim.x + threadIdx.x;
  int b = blockIdx.y;
  int t = tgt[(size_t)b*E_ + e];
  atomicAdd(&cnt[b*N_ + t], 1);
}

__global__ void k_scan(const int* __restrict__ cnt, int* __restrict__ off, int* __restrict__ cursor){
  int b = blockIdx.x;
  __shared__ int wsum[16];
  __shared__ int carry_s;
  int lane = threadIdx.x & 63, wid = threadIdx.x >> 6;
  if (threadIdx.x == 0){ carry_s = 0; off[b*(N_+1)] = 0; }
  __syncthreads();
  for (int base = 0; base < N_; base += 1024){
    int i = base + threadIdx.x;
    int v = (i < N_) ? cnt[b*N_ + i] : 0;
    int x = v;
    #pragma unroll
    for (int d = 1; d < 64; d <<= 1){
      int y = __shfl_up(x, d);
      if (lane >= d) x += y;
    }
    if (lane == 63) wsum[wid] = x;
    __syncthreads();
    if (wid == 0 && lane < 16){
      int w = wsum[lane];
      #pragma unroll
      for (int d = 1; d < 16; d <<= 1){
        int y = __shfl_up(w, d, 16);
        if (lane >= d) w += y;
      }
      wsum[lane] = w;
    }
    __syncthreads();
    int excl = (wid ? wsum[wid-1] : 0) + carry_s;
    if (i < N_){
      int inc = x + excl;
      off[b*(N_+1) + i + 1] = inc;
      cursor[b*N_ + i] = inc - v;
    }
    __syncthreads();
    if (threadIdx.x == 0) carry_s += wsum[15];
    __syncthreads();
  }
}

__global__ void k_scatter(const int* __restrict__ src, const int* __restrict__ tgt,
                          int* __restrict__ cursor, int* __restrict__ csr){
  int e = blockIdx.x*blockDim.x + threadIdx.x;
  int b = blockIdx.y;
  int t = tgt[(size_t)b*E_ + e];
  int pos = atomicAdd(&cursor[b*N_ + t], 1);
  csr[(size_t)b*E_ + pos] = src[(size_t)b*E_ + e];
}

// ---------------- prep: Wa tables + W transpose/cast, all 3 layers ----------------
__global__ void k_prep(const float* __restrict__ W0, const float* __restrict__ W1, const float* __restrict__ W2,
                       const float* __restrict__ as0, const float* __restrict__ as1, const float* __restrict__ as2,
                       const float* __restrict__ ad0, const float* __restrict__ ad1, const float* __restrict__ ad2,
                       float* __restrict__ wasA, float* __restrict__ wadA, unsigned short* __restrict__ wtA){
  int l = blockIdx.y;
  const float* W   = (l==0)?W0:(l==1)?W1:W2;
  const float* asp = (l==0)?as0:(l==1)?as1:as2;
  const float* adp = (l==0)?ad0:(l==1)?ad1:ad2;
  if (blockIdx.x < 256){
    int i = blockIdx.x*256 + threadIdx.x;     // i = c*H_ + k
    int c = i >> 7, k = i & 127;
    wtA[(size_t)l*HH_*H_ + i] = f2b(W[(size_t)k*HH_ + c]);
  } else {
    int j = (blockIdx.x - 256)*256 + threadIdx.x;   // j = k*4 + h
    if (j < H_*HEADS_){
      int k = j >> 2, h = j & 3;
      const float* wrow = W + (size_t)k*HH_ + h*H_;
      const float* asr = asp + h*H_;
      const float* adr = adp + h*H_;
      float ss = 0.f, sd = 0.f;
      for (int c = 0; c < H_; ++c){ float w = wrow[c]; ss += w*asr[c]; sd += w*adr[c]; }
      wasA[l*HH_ + j] = ss; wadA[l*HH_ + j] = sd;
    }
  }
}

// ---------------- layer-1: cast x->bf16 + logits (one wave per row) ----------------
__global__ __launch_bounds__(256) void k_cast_logits(const float* __restrict__ X,
    const float* __restrict__ was, const float* __restrict__ wad,
    unsigned short* __restrict__ Xb, float* __restrict__ es, float* __restrict__ ed){
  int gw = (blockIdx.x*blockDim.x + threadIdx.x) >> 6;
  int lane = threadIdx.x & 63;
  float2 v = *(const float2*)(X + (size_t)gw*H_ + lane*2);
  unsigned int o = ((unsigned int)f2b(v.y) << 16) | (unsigned int)f2b(v.x);
  *(unsigned int*)(Xb + (size_t)gw*H_ + lane*2) = o;
  int c = lane*2;
  const f32x4* w4 = (const f32x4*)was;
  const f32x4* d4 = (const f32x4*)wad;
  f32x4 se = v.x*w4[c] + v.y*w4[c+1];
  f32x4 de = v.x*d4[c] + v.y*d4[c+1];
  #pragma unroll
  for (int d = 1; d < 64; d <<= 1){
    se.x += __shfl_xor(se.x,d); se.y += __shfl_xor(se.y,d);
    se.z += __shfl_xor(se.z,d); se.w += __shfl_xor(se.w,d);
    de.x += __shfl_xor(de.x,d); de.y += __shfl_xor(de.y,d);
    de.z += __shfl_xor(de.z,d); de.w += __shfl_xor(de.w,d);
  }
  if (lane == 0){
    *(float4*)(es + (size_t)gw*4) = make_float4(se.x, se.y, se.z, se.w);
    *(float4*)(ed + (size_t)gw*4) = make_float4(de.x, de.y, de.z, de.w);
  }
}

// ---------------- h = x @ W  (bf16 MFMA 16x16x32; 64x64 tile) ----------------
__global__ __launch_bounds__(256) void k_gemm_mfma(const unsigned short* __restrict__ Xb,
    const unsigned short* __restrict__ Wt, unsigned short* __restrict__ Hb){
  __shared__ unsigned short xs[64*128];
  __shared__ unsigned short ws[64*128];
  int row0 = blockIdx.x * 64, col0 = blockIdx.y * 64;
  int tid = threadIdx.x;
  int ch = tid & 15, r0 = tid >> 4;
  #pragma unroll
  for (int p = 0; p < 4; ++p){
    int r = r0 + p*16;
    int sc = ch ^ (r & 7);
    *(uint4*)(&xs[r*128 + sc*8]) = *(const uint4*)(Xb + (size_t)(row0 + r)*H_ + ch*8);
    *(uint4*)(&ws[r*128 + sc*8]) = *(const uint4*)(Wt + (size_t)(col0 + r)*H_ + ch*8);
  }
  __syncthreads();
  int w = tid >> 6, l = tid & 63;
  int lr = l & 15, q = l >> 4;
  f32x4 z = {0.f, 0.f, 0.f, 0.f};
  f32x4 acc[4] = {z, z, z, z};
  int arow = w*16 + lr;
  #pragma unroll
  for (int kf = 0; kf < 4; ++kf){
    int bch = kf*4 + q;
    bf16x8 a = *(const bf16x8*)(&xs[arow*128 + (bch ^ (arow & 7))*8]);
    #pragma unroll
    for (int cf = 0; cf < 4; ++cf){
      int brow = cf*16 + lr;
      bf16x8 bfr = *(const bf16x8*)(&ws[brow*128 + (bch ^ (brow & 7))*8]);
      acc[cf] = __builtin_amdgcn_mfma_f32_16x16x32_bf16(a, bfr, acc[cf], 0, 0, 0);
    }
  }
  #pragma unroll
  for (int cf = 0; cf < 4; ++cf){
    #pragma unroll
    for (int rg = 0; rg < 4; ++rg){
      int row = row0 + w*16 + q*4 + rg;
      int col = col0 + cf*16 + lr;
      Hb[(size_t)row*HH_ + col] = f2b(acc[cf][rg]);
    }
  }
}

// ---------------- aggregate + (LN+ReLU + next-layer logits | final write) ----------------
template<bool FINAL>
__global__ __launch_bounds__(256, 4) void k_aggregate(
    const unsigned short* __restrict__ Hb,
    const float* __restrict__ es, const float* __restrict__ ed,
    const int* __restrict__ off, const int* __restrict__ csr,
    const float* __restrict__ bias,
    const float* __restrict__ wasN, const float* __restrict__ wadN,
    const float* __restrict__ lng, const float* __restrict__ lnb,
    float* __restrict__ Yout, unsigned short* __restrict__ Xbout,
    float* __restrict__ esN, float* __restrict__ edN)
{
  __shared__ float alpha_s[4][4][68];   // [wave][head][edge], stride 68 to spread banks
  __shared__ int   srcn_s[4][64];
  __shared__ float orow_s[4][128];
  int wv = threadIdx.x >> 6, lane = threadIdx.x & 63;
  int gw = blockIdx.x*4 + wv;
  int b = gw / N_, t = gw - b*N_;
  const float4 edv = *(const float4*)(ed + (size_t)gw*4);
  int start = off[b*(N_+1) + t];
  int deg = off[b*(N_+1) + t + 1] - start;
  int total = deg + 1;                       // + implicit self-loop
  const int* lst = csr + (size_t)b*E_ + start;
  const float* esb = es + (size_t)b*N_*4;
  int head = lane >> 4;
  int cb = head*H_ + (lane & 15)*8;
  const unsigned short* hbase = Hb + (size_t)b*N_*HH_;
  f32x2 zz = {0.f, 0.f};
  f32x2 ac[4] = {zz, zz, zz, zz};

  if (total <= 64){
    // ---- phase A: one lane per edge; padded lanes get alpha=0, src=t ----
    bool valid = lane < total;
    int srcn = (lane < deg) ? lst[lane] : t;
    srcn_s[wv][lane] = srcn;
    float4 ev = *(const float4*)(esb + (size_t)srcn*4);   // issued early
    __builtin_amdgcn_wave_barrier();
    // chunk-0 prefetch: issue 8 gathers now, consume after softmax
    int4 s0 = *(const int4*)(&srcn_s[wv][0]);
    int4 s1 = *(const int4*)(&srcn_s[wv][4]);
    uint4 g0 = *(const uint4*)(hbase + (size_t)s0.x*HH_ + cb);
    uint4 g1 = *(const uint4*)(hbase + (size_t)s0.y*HH_ + cb);
    uint4 g2 = *(const uint4*)(hbase + (size_t)s0.z*HH_ + cb);
    uint4 g3 = *(const uint4*)(hbase + (size_t)s0.w*HH_ + cb);
    uint4 g4 = *(const uint4*)(hbase + (size_t)s1.x*HH_ + cb);
    uint4 g5 = *(const uint4*)(hbase + (size_t)s1.y*HH_ + cb);
    uint4 g6 = *(const uint4*)(hbase + (size_t)s1.z*HH_ + cb);
    uint4 g7 = *(const uint4*)(hbase + (size_t)s1.w*HH_ + cb);

    float e0 = valid ? lrelu(ev.x + edv.x) : -1e30f;
    float e1 = valid ? lrelu(ev.y + edv.y) : -1e30f;
    float e2 = valid ? lrelu(ev.z + edv.z) : -1e30f;
    float e3 = valid ? lrelu(ev.w + edv.w) : -1e30f;
    float M0 = e0, M1 = e1, M2 = e2, M3 = e3;
    #pragma unroll
    for (int d = 1; d < 64; d <<= 1){
      M0 = fmaxf(M0, __shfl_xor(M0, d)); M1 = fmaxf(M1, __shfl_xor(M1, d));
      M2 = fmaxf(M2, __shfl_xor(M2, d)); M3 = fmaxf(M3, __shfl_xor(M3, d));
    }
    float p0 = valid ? __expf(e0 - M0) : 0.f;
    float p1 = valid ? __expf(e1 - M1) : 0.f;
    float p2 = valid ? __expf(e2 - M2) : 0.f;
    float p3 = valid ? __expf(e3 - M3) : 0.f;
    float S0 = p0, S1 = p1, S2 = p2, S3 = p3;
    #pragma unroll
    for (int d = 1; d < 64; d <<= 1){
      S0 += __shfl_xor(S0, d); S1 += __shfl_xor(S1, d);
      S2 += __shfl_xor(S2, d); S3 += __shfl_xor(S3, d);
    }
    alpha_s[wv][0][lane] = p0/S0;
    alpha_s[wv][1][lane] = p1/S1;
    alpha_s[wv][2][lane] = p2/S2;
    alpha_s[wv][3][lane] = p3/S3;
    __builtin_amdgcn_wave_barrier();

    const float* alp = &alpha_s[wv][head][0];
    const int*   srp = &srcn_s[wv][0];
    // consume chunk 0
    {
      float4 al0 = *(const float4*)(alp);
      float4 al1 = *(const float4*)(alp + 4);
      acc_row(ac, al0.x, g0); acc_row(ac, al0.y, g1);
      acc_row(ac, al0.z, g2); acc_row(ac, al0.w, g3);
      acc_row(ac, al1.x, g4); acc_row(ac, al1.y, g5);
      acc_row(ac, al1.z, g6); acc_row(ac, al1.w, g7);
    }
    // chunks 1..nc-1: single-BB 8-wide batches (issue 8, consume 8 FIFO)
    int nc = (total + 7) >> 3;
    for (int ck = 1; ck < nc; ++ck){
      int base = ck*8;
      float4 al0 = *(const float4*)(alp + base);
      float4 al1 = *(const float4*)(alp + base + 4);
      int4 c0 = *(const int4*)(srp + base);
      int4 c1 = *(const int4*)(srp + base + 4);
      uint4 h0 = *(const uint4*)(hbase + (size_t)c0.x*HH_ + cb);
      uint4 h1 = *(const uint4*)(hbase + (size_t)c0.y*HH_ + cb);
      uint4 h2 = *(const uint4*)(hbase + (size_t)c0.z*HH_ + cb);
      uint4 h3 = *(const uint4*)(hbase + (size_t)c0.w*HH_ + cb);
      uint4 h4 = *(const uint4*)(hbase + (size_t)c1.x*HH_ + cb);
      uint4 h5 = *(const uint4*)(hbase + (size_t)c1.y*HH_ + cb);
      uint4 h6 = *(const uint4*)(hbase + (size_t)c1.z*HH_ + cb);
      uint4 h7 = *(const uint4*)(hbase + (size_t)c1.w*HH_ + cb);
      acc_row(ac, al0.x, h0); acc_row(ac, al0.y, h1);
      acc_row(ac, al0.z, h2); acc_row(ac, al0.w, h3);
      acc_row(ac, al1.x, h4); acc_row(ac, al1.y, h5);
      acc_row(ac, al1.z, h6); acc_row(ac, al1.w, h7);
    }
  } else {
    // ---- slow path (deg >= 64): online softmax + inline alpha ----
    float m0=-1e30f, m1=-1e30f, m2=-1e30f, m3=-1e30f;
    float s0=0.f, s1=0.f, s2=0.f, s3=0.f;
    for (int i2 = lane; i2 <= deg; i2 += 64){
      int srcn = (i2 < deg) ? lst[i2] : t;
      float4 ev = *(const float4*)(esb + (size_t)srcn*4);
      float e0 = lrelu(ev.x + edv.x);
      float e1 = lrelu(ev.y + edv.y);
      float e2 = lrelu(ev.z + edv.z);
      float e3 = lrelu(ev.w + edv.w);
      float nm;
      nm = fmaxf(m0, e0); s0 = s0*__expf(m0-nm) + __expf(e0-nm); m0 = nm;
      nm = fmaxf(m1, e1); s1 = s1*__expf(m1-nm) + __expf(e1-nm); m1 = nm;
      nm = fmaxf(m2, e2); s2 = s2*__expf(m2-nm) + __expf(e2-nm); m2 = nm;
      nm = fmaxf(m3, e3); s3 = s3*__expf(m3-nm) + __expf(e3-nm); m3 = nm;
    }
    #pragma unroll
    for (int d = 1; d < 64; d <<= 1){
      float om, os, nm;
      om = __shfl_xor(m0, d); os = __shfl_xor(s0, d); nm = fmaxf(m0, om);
      s0 = s0*__expf(m0-nm) + os*__expf(om-nm); m0 = nm;
      om = __shfl_xor(m1, d); os = __shfl_xor(s1, d); nm = fmaxf(m1, om);
      s1 = s1*__expf(m1-nm) + os*__expf(om-nm); m1 = nm;
      om = __shfl_xor(m2, d); os = __shfl_xor(s2, d); nm = fmaxf(m2, om);
      s2 = s2*__expf(m2-nm) + os*__expf(om-nm); m2 = nm;
      om = __shfl_xor(m3, d); os = __shfl_xor(s3, d); nm = fmaxf(m3, om);
      s3 = s3*__expf(m3-nm) + os*__expf(om-nm); m3 = nm;
    }
    float mh, sh, edh;
    if      (head == 0){ mh = m0; sh = s0; edh = edv.x; }
    else if (head == 1){ mh = m1; sh = s1; edh = edv.y; }
    else if (head == 2){ mh = m2; sh = s2; edh = edv.z; }
    else               { mh = m3; sh = s3; edh = edv.w; }
    float rh = 1.0f / sh;
    for (int i2 = 0; i2 < total; ++i2){
      int srcn = (i2 < deg) ? lst[i2] : t;
      float eh = esb[(size_t)srcn*4 + head];
      float al = __expf(lrelu(eh + edh) - mh) * rh;
      uint4 hA = *(const uint4*)(hbase + (size_t)srcn*HH_ + cb);
      acc_row(ac, al, hA);
    }
  }

  // ---- epilogue: head mean ----
  float a[8] = {ac[0].x, ac[0].y, ac[1].x, ac[1].y, ac[2].x, ac[2].y, ac[3].x, ac[3].y};
  #pragma unroll
  for (int d = 16; d < 64; d <<= 1)
    #pragma unroll
    for (int j = 0; j < 8; j++) a[j] += __shfl_xor(a[j], d);

  int c = (lane & 15)*8;
  if (FINAL){
    if (lane < 16){
      float4 o0 = make_float4(0.25f*a[0]+bias[c+0], 0.25f*a[1]+bias[c+1],
                              0.25f*a[2]+bias[c+2], 0.25f*a[3]+bias[c+3]);
      float4 o1 = make_float4(0.25f*a[4]+bias[c+4], 0.25f*a[5]+bias[c+5],
                              0.25f*a[6]+bias[c+6], 0.25f*a[7]+bias[c+7]);
      *(float4*)(Yout + (size_t)gw*H_ + c)     = o0;
      *(float4*)(Yout + (size_t)gw*H_ + c + 4) = o1;
    }
  } else {
    float o[8];
    #pragma unroll
    for (int j = 0; j < 8; j++) o[j] = 0.25f*a[j] + bias[c+j];
    float ss = 0.f;
    #pragma unroll
    for (int j = 0; j < 8; j++) ss += o[j];
    #pragma unroll
    for (int d = 1; d < 16; d <<= 1) ss += __shfl_xor(ss, d);
    float mu = ss * (1.f/H_);
    float vv = 0.f;
    #pragma unroll
    for (int j = 0; j < 8; j++){ float dx = o[j]-mu; vv += dx*dx; }
    #pragma unroll
    for (int d = 1; d < 16; d <<= 1) vv += __shfl_xor(vv, d);
    float inv = rsqrtf(vv*(1.f/H_) + 1e-5f);
    float4 g0 = *(const float4*)(lng + c), g1 = *(const float4*)(lng + c + 4);
    float4 b0 = *(const float4*)(lnb + c), b1 = *(const float4*)(lnb + c + 4);
    float gg[8] = {g0.x,g0.y,g0.z,g0.w,g1.x,g1.y,g1.z,g1.w};
    float bb[8] = {b0.x,b0.y,b0.z,b0.w,b1.x,b1.y,b1.z,b1.w};
    float oo[8];
    #pragma unroll
    for (int j = 0; j < 8; j++) oo[j] = fmaxf((o[j]-mu)*inv*gg[j] + bb[j], 0.f);
    if (lane < 16){
      uint4 up;
      up.x = ((unsigned int)f2b(oo[1]) << 16) | f2b(oo[0]);
      up.y = ((unsigned int)f2b(oo[3]) << 16) | f2b(oo[2]);
      up.z = ((unsigned int)f2b(oo[5]) << 16) | f2b(oo[4]);
      up.w = ((unsigned int)f2b(oo[7]) << 16) | f2b(oo[6]);
      *(uint4*)(Xbout + (size_t)gw*H_ + lane*8) = up;
      *(float4*)(&orow_s[wv][c])     = make_float4(oo[0], oo[1], oo[2], oo[3]);
      *(float4*)(&orow_s[wv][c + 4]) = make_float4(oo[4], oo[5], oo[6], oo[7]);
    }
    __builtin_amdgcn_wave_barrier();
    float pe = 0.f, pd = 0.f;
    #pragma unroll
    for (int j = 0; j < 8; j++){
      float xv = orow_s[wv][c + j];
      pe += xv * wasN[(c + j)*4 + head];
      pd += xv * wadN[(c + j)*4 + head];
    }
    #pragma unroll
    for (int d = 1; d < 16; d <<= 1){ pe += __shfl_xor(pe, d); pd += __shfl_xor(pd, d); }
    if ((lane & 15) == 0){
      esN[(size_t)gw*4 + head] = pe;
      edN[(size_t)gw*4 + head] = pd;
    }
  }
}

extern "C" void kernel_launch(void* const* d_in, const int* in_sizes, int n_in,
                              void* d_out, int out_size, void* d_ws, size_t ws_size,
                              hipStream_t stream){
  const float* x0   = (const float*)d_in[0];
  const int*   srcI = (const int*)d_in[1];
  const int*   tgtI = (const int*)d_in[2];
  const float* Wl[3]  = {(const float*)d_in[3], (const float*)d_in[7],  (const float*)d_in[11]};
  const float* asl[3] = {(const float*)d_in[4], (const float*)d_in[8],  (const float*)d_in[12]};
  const float* adl[3] = {(const float*)d_in[5], (const float*)d_in[9],  (const float*)d_in[13]};
  const float* bl[3]  = {(const float*)d_in[6], (const float*)d_in[10], (const float*)d_in[14]};
  const float* lng[2] = {(const float*)d_in[15], (const float*)d_in[17]};
  const float* lnb[2] = {(const float*)d_in[16], (const float*)d_in[18]};

  char* p = (char*)d_ws;
  auto carve = [&](size_t bytes) -> void* {
    void* r = (void*)p; p += (bytes + 255) & ~(size_t)255; return r;
  };
  int*   off    = (int*)carve((size_t)B_*(N_+1)*4);
  int*   cnt    = (int*)carve((size_t)B_*N_*4);
  int*   cursor = (int*)carve((size_t)B_*N_*4);
  int*   csr    = (int*)carve((size_t)B_*E_*4);
  float* es2[2] = {(float*)carve((size_t)NROWS*4*4), (float*)carve((size_t)NROWS*4*4)};
  float* ed2[2] = {(float*)carve((size_t)NROWS*4*4), (float*)carve((size_t)NROWS*4*4)};
  float* wasA   = (float*)carve((size_t)3*HH_*4);
  float* wadA   = (float*)carve((size_t)3*HH_*4);
  unsigned short* wtA  = (unsigned short*)carve((size_t)3*HH_*H_*2);
  unsigned short* hbuf = (unsigned short*)carve((size_t)NROWS*HH_*2);
  unsigned short* xbf  = (unsigned short*)carve((size_t)NROWS*H_*2);

  hipMemsetAsync(cnt, 0, (size_t)B_*N_*4, stream);
  k_count  <<<dim3(E_/256, B_), 256, 0, stream>>>(tgtI, cnt);
  k_scan   <<<B_, 1024, 0, stream>>>(cnt, off, cursor);
  k_scatter<<<dim3(E_/256, B_), 256, 0, stream>>>(srcI, tgtI, cursor, csr);
  k_prep   <<<dim3(258, 3), 256, 0, stream>>>(Wl[0], Wl[1], Wl[2],
                                              asl[0], asl[1], asl[2],
                                              adl[0], adl[1], adl[2],
                                              wasA, wadA, wtA);
  k_cast_logits<<<NROWS/4, 256, 0, stream>>>(x0, wasA, wadA, xbf, es2[0], ed2[0]);

  for (int l = 0; l < 3; ++l){
    k_gemm_mfma<<<dim3(NROWS/64, HH_/64), 256, 0, stream>>>(xbf, wtA + (size_t)l*HH_*H_, hbuf);
    int cur = l & 1, nxt = cur ^ 1;
    if (l < 2){
      k_aggregate<false><<<NROWS/4, 256, 0, stream>>>(hbuf, es2[cur], ed2[cur], off, csr, bl[l],
          wasA + (size_t)(l+1)*HH_, wadA + (size_t)(l+1)*HH_, lng[l], lnb[l],
          nullptr, xbf, es2[nxt], ed2[nxt]);
    } else {
      k_aggregate<true><<<NROWS/4, 256, 0, stream>>>(hbuf, es2[cur], ed2[cur], off, csr, bl[l],
          nullptr, nullptr, nullptr, nullptr,
          (float*)d_out, nullptr, nullptr, nullptr);
    }
  }
}